// Round 2
// baseline (387.222 us; speedup 1.0000x reference)
//
#include <hip/hip_runtime.h>
#include <hip/hip_bf16.h>
#include <cstdint>
#include <cstddef>
#include <type_traits>

#define INTER 2816

typedef __bf16 bf16x8 __attribute__((ext_vector_type(8)));
typedef float f32x4 __attribute__((ext_vector_type(4)));
using bf16 = __hip_bfloat16;
using u16 = unsigned short;

__device__ __forceinline__ u16 f2bu(float f) {
  bf16 h = __float2bfloat16(f);
  return *reinterpret_cast<u16*>(&h);
}
__device__ __forceinline__ float bu2f(u16 u) {
  bf16 h = *reinterpret_cast<bf16*>(&u);
  return __bfloat162float(h);
}

// Stage 8 contiguous elements as bf16 (16B) into LDS.
__device__ __forceinline__ void stage8(u16* dst, const float* src) {
  const float4 a = *(const float4*)(src);
  const float4 b = *(const float4*)(src + 4);
  u16 tmp[8] = {f2bu(a.x), f2bu(a.y), f2bu(a.z), f2bu(a.w),
                f2bu(b.x), f2bu(b.y), f2bu(b.z), f2bu(b.w)};
  *(uint4*)dst = *(uint4*)tmp;
}
__device__ __forceinline__ void stage8(u16* dst, const u16* src) {
  *(uint4*)dst = *(const uint4*)src;
}

// ---------------------------------------------------------------------------
// NT GEMM: C[M,N] = A[M,K] * Bt[N,K]^T. AT/BT in {float, u16(bf16)};
// compute in bf16 MFMA, f32 accumulate. OT in {float, u16(bf16)}.
// 128x128 tile, 4 waves x (4x4) 16x16x32 mfma, BK=32.
// M,N multiples of 128; K multiple of 32.
// ---------------------------------------------------------------------------
template <typename AT, typename BT, typename OT>
__global__ __launch_bounds__(256, 2)
void gemm_nt(const AT* __restrict__ A, const BT* __restrict__ Bt,
             OT* __restrict__ C, int M, int N, int K) {
  __shared__ u16 As[128][40];  // pad 32->40: stride 80B breaks pow2 conflicts
  __shared__ u16 Bs[128][40];
  const int m0 = blockIdx.x * 128;
  const int n0 = blockIdx.y * 128;
  const int tid = threadIdx.x;
  const int lane = tid & 63;
  const int wv = tid >> 6;
  const int wm = wv & 1, wn = wv >> 1;
  const int lr = lane & 15;
  const int lq = lane >> 4;

  f32x4 acc[4][4];
#pragma unroll
  for (int i = 0; i < 4; ++i)
#pragma unroll
    for (int j = 0; j < 4; ++j) acc[i][j] = (f32x4){0.f, 0.f, 0.f, 0.f};

  const int sr = tid >> 2;       // staging row 0..63 (+64 second pass)
  const int sc = (tid & 3) * 8;  // staging col (elements)

  for (int kb = 0; kb < K; kb += 32) {
#pragma unroll
    for (int it = 0; it < 2; ++it) {
      const int r = sr + it * 64;
      stage8(&As[r][sc], &A[(size_t)(m0 + r) * K + kb + sc]);
      stage8(&Bs[r][sc], &Bt[(size_t)(n0 + r) * K + kb + sc]);
    }
    __syncthreads();
    bf16x8 af[4], bfr[4];
#pragma unroll
    for (int i = 0; i < 4; ++i)
      af[i] = *(const bf16x8*)(&As[wm * 64 + i * 16 + lr][lq * 8]);
#pragma unroll
    for (int j = 0; j < 4; ++j)
      bfr[j] = *(const bf16x8*)(&Bs[wn * 64 + j * 16 + lr][lq * 8]);
#pragma unroll
    for (int i = 0; i < 4; ++i)
#pragma unroll
      for (int j = 0; j < 4; ++j)
        acc[i][j] = __builtin_amdgcn_mfma_f32_16x16x32_bf16(af[i], bfr[j],
                                                            acc[i][j], 0, 0, 0);
    __syncthreads();
  }

#pragma unroll
  for (int i = 0; i < 4; ++i)
#pragma unroll
    for (int j = 0; j < 4; ++j) {
      const int col = n0 + wn * 64 + j * 16 + lr;
#pragma unroll
      for (int r = 0; r < 4; ++r) {
        const int row = m0 + wm * 64 + i * 16 + lq * 4 + r;
        const float v = acc[i][j][r];
        if constexpr (std::is_same_v<OT, float>) {
          C[(size_t)row * N + col] = v;
        } else {
          C[(size_t)row * N + col] = f2bu(v);
        }
      }
    }
}

// ---------------------------------------------------------------------------
// x_ffn[row, c] = silu(gu[row, c]) * gu[row, INTER + c]   (bf16 in/out)
// ---------------------------------------------------------------------------
__global__ void silu_mul(const u16* __restrict__ gu, u16* __restrict__ xffn) {
  const int c = blockIdx.x * 256 + threadIdx.x;
  const int row = blockIdx.y;
  const float g = bu2f(gu[(size_t)row * (2 * INTER) + c]);
  const float u = bu2f(gu[(size_t)row * (2 * INTER) + INTER + c]);
  const float s = g / (1.f + __expf(-g));
  xffn[(size_t)row * INTER + c] = f2bu(s * u);
}

// ---------------------------------------------------------------------------
// wm2[n, c] (128 x INTER bf16, zero-padded past 63): n = o*9+tap
// cwT[k, c] (9 x INTER, f32): conv_w[c, k] transposed for coalesced reads
// ---------------------------------------------------------------------------
__global__ void prep_weights(const float* __restrict__ w_metric,
                             const float* __restrict__ conv_w,
                             u16* __restrict__ wm2, float* __restrict__ cwT) {
  const int c = blockIdx.x * 256 + threadIdx.x;  // 0..INTER-1
  const int y = blockIdx.y;                      // 0..136
  if (y < 128) {
    float v = 0.f;
    if (y < 63) {
      const int o = y / 9, tap = y % 9;
      v = w_metric[((size_t)o * INTER + c) * 9 + tap];
    }
    wm2[(size_t)y * INTER + c] = f2bu(v);
  } else {
    const int k = y - 128;
    cwT[(size_t)k * INTER + c] = conv_w[(size_t)c * 9 + k];
  }
}

// ---------------------------------------------------------------------------
// Per (b, pixel): sum 9 shifted taps of q -> p[0..6], add bias, emit 9
// sample records {y0, x0, ty, tx}.
// ---------------------------------------------------------------------------
__global__ void offsets_kernel(const float* __restrict__ q,
                               const float* __restrict__ b_metric,
                               int4* __restrict__ samp) {
  const int t = blockIdx.x * 256 + threadIdx.x;  // 0..2047
  const int b = t >> 10, l = t & 1023;
  const int i = l >> 5, j = l & 31;
  float p[7];
#pragma unroll
  for (int o = 0; o < 7; ++o) p[o] = b_metric[o];
#pragma unroll
  for (int tap = 0; tap < 9; ++tap) {
    const int ii = i + tap / 3 - 1;
    const int jj = j + tap % 3 - 1;
    if (ii >= 0 && ii < 32 && jj >= 0 && jj < 32) {
      const size_t base = ((size_t)b * 1024 + ii * 32 + jj) * 128;
#pragma unroll
      for (int o = 0; o < 7; ++o) p[o] += q[base + o * 9 + tap];
    }
  }
  const float m00 = p[0], m01 = p[1], m10 = p[2], m11 = p[3];
  const float dry = p[4], drx = p[5];
  const float sc = tanhf(p[6]);
#pragma unroll
  for (int k = 0; k < 9; ++k) {
    const float pyk = (float)(k / 3 - 1), pxk = (float)(k % 3 - 1);
    const float offy = sc * (m00 * pyk + m01 * pxk) + dry;
    const float offx = sc * (m10 * pyk + m11 * pxk) + drx;
    const float posy = (float)i + pyk + offy;
    const float posx = (float)j + pxk + offx;
    const float y0f = floorf(posy), x0f = floorf(posx);
    int4 s;
    s.x = (int)y0f;
    s.y = (int)x0f;
    s.z = __float_as_int(posy - y0f);
    s.w = __float_as_int(posx - x0f);
    samp[((size_t)b * 9 + k) * 1024 + l] = s;
  }
}

// ---------------------------------------------------------------------------
// Deformable depthwise conv: block = one (b, pixel) x 256 channels.
// Gathers coalesced across c (x_ffn channel-contiguous).
// ---------------------------------------------------------------------------
__global__ void deform_kernel(const u16* __restrict__ xffn,
                              const int4* __restrict__ samp,
                              const float* __restrict__ cwT,
                              const float* __restrict__ conv_b,
                              u16* __restrict__ gridout) {
  const int c = blockIdx.x * 256 + threadIdx.x;
  const int l = blockIdx.y;
  const int b = blockIdx.z;
  const size_t pixbase = (size_t)b * 1024;
  float acc = conv_b[c];
#pragma unroll
  for (int k = 0; k < 9; ++k) {
    const int4 s = samp[((size_t)b * 9 + k) * 1024 + l];
    const int y0 = s.x, x0 = s.y;
    const float ty = __int_as_float(s.z), tx = __int_as_float(s.w);
    const int y1 = y0 + 1, x1 = x0 + 1;
    const bool vy0 = (y0 >= 0) && (y0 < 32);
    const bool vy1 = (y1 >= 0) && (y1 < 32);
    const bool vx0 = (x0 >= 0) && (x0 < 32);
    const bool vx1 = (x1 >= 0) && (x1 < 32);
    float v00 = 0.f, v01 = 0.f, v10 = 0.f, v11 = 0.f;
    if (vy0 && vx0) v00 = bu2f(xffn[(pixbase + y0 * 32 + x0) * INTER + c]);
    if (vy0 && vx1) v01 = bu2f(xffn[(pixbase + y0 * 32 + x1) * INTER + c]);
    if (vy1 && vx0) v10 = bu2f(xffn[(pixbase + y1 * 32 + x0) * INTER + c]);
    if (vy1 && vx1) v11 = bu2f(xffn[(pixbase + y1 * 32 + x1) * INTER + c]);
    const float bl = (1.f - ty) * ((1.f - tx) * v00 + tx * v01) +
                     ty * ((1.f - tx) * v10 + tx * v11);
    acc += bl * cwT[(size_t)k * INTER + c];
  }
  gridout[(pixbase + l) * INTER + c] = f2bu(acc);
}

// ---------------------------------------------------------------------------
extern "C" void kernel_launch(void* const* d_in, const int* in_sizes, int n_in,
                              void* d_out, int out_size, void* d_ws,
                              size_t ws_size, hipStream_t stream) {
  const float* x         = (const float*)d_in[0];
  const float* w_gate_up = (const float*)d_in[1];
  const float* w_metric  = (const float*)d_in[2];
  const float* b_metric  = (const float*)d_in[3];
  const float* conv_w    = (const float*)d_in[4];
  const float* conv_b    = (const float*)d_in[5];
  const float* w_down    = (const float*)d_in[6];
  float* out = (float*)d_out;

  // Workspace (37.1 MB peak, lifetimes allow overlap):
  //   gu      [0, 23.1)    bf16, dead after silu_mul
  //   q       [12, 13)     f32, written step 4 (gu dead), dead after step 5
  //   gridout [0, 11.6)    bf16, written step 6 (q dead), read step 7
  //   samp    [14, 14.3)
  //   xffn    [24, 35.6)   bf16
  //   wm2     [36, 36.7)   bf16
  //   cwT     [37, 37.1)   f32
  char* w = (char*)d_ws;
  u16* gu       = (u16*)(w);
  u16* gridout  = (u16*)(w);
  float* q      = (float*)(w + (12u << 20));
  int4* samp    = (int4*)(w + (14u << 20));
  u16* xffn     = (u16*)(w + (24u << 20));
  u16* wm2      = (u16*)(w + (36u << 20));
  float* cwT    = (float*)(w + (37u << 20));

  // 1) gu = x @ w_gate_up^T          (2048 x 5632 x 1024)
  gemm_nt<float, float, u16><<<dim3(16, 44), 256, 0, stream>>>(
      x, w_gate_up, gu, 2048, 2 * INTER, 1024);
  // 2) x_ffn = silu(gate) * up
  silu_mul<<<dim3(11, 2048), 256, 0, stream>>>(gu, xffn);
  // 3) weight repacks
  prep_weights<<<dim3(11, 137), 256, 0, stream>>>(w_metric, conv_w, wm2, cwT);
  // 4) q = x_ffn @ wm2^T             (2048 x 128 x 2816), metric conv as GEMM
  gemm_nt<u16, u16, float><<<dim3(16, 1), 256, 0, stream>>>(
      xffn, wm2, q, 2048, 128, INTER);
  // 5) tap-sum + offsets -> sample records
  offsets_kernel<<<8, 256, 0, stream>>>(q, b_metric, samp);
  // 6) deformable depthwise conv
  deform_kernel<<<dim3(11, 1024, 2), 256, 0, stream>>>(xffn, samp, cwT,
                                                       conv_b, gridout);
  // 7) out = grid_out @ w_down^T     (2048 x 1024 x 2816)
  gemm_nt<u16, float, float><<<dim3(16, 8), 256, 0, stream>>>(
      gridout, w_down, out, 2048, 1024, INTER);
}

// Round 3
// 310.455 us; speedup vs baseline: 1.2473x; 1.2473x over previous
//
#include <hip/hip_runtime.h>
#include <hip/hip_bf16.h>
#include <cstdint>
#include <cstddef>
#include <type_traits>

#define INTER 2816

typedef __bf16 bf16x8 __attribute__((ext_vector_type(8)));
typedef float f32x4 __attribute__((ext_vector_type(4)));
typedef unsigned short u16x8 __attribute__((ext_vector_type(8)));
using bf16 = __hip_bfloat16;
using u16 = unsigned short;

__device__ __forceinline__ u16 f2bu(float f) {
  bf16 h = __float2bfloat16(f);
  return *reinterpret_cast<u16*>(&h);
}
__device__ __forceinline__ float bu2f(u16 u) {
  bf16 h = *reinterpret_cast<bf16*>(&u);
  return __bfloat162float(h);
}

// Stage 8 contiguous elements as bf16 (16B) into LDS.
__device__ __forceinline__ void stage8(u16* dst, const float* src) {
  const float4 a = *(const float4*)(src);
  const float4 b = *(const float4*)(src + 4);
  u16 tmp[8] = {f2bu(a.x), f2bu(a.y), f2bu(a.z), f2bu(a.w),
                f2bu(b.x), f2bu(b.y), f2bu(b.z), f2bu(b.w)};
  *(uint4*)dst = *(uint4*)tmp;
}
__device__ __forceinline__ void stage8(u16* dst, const u16* src) {
  *(uint4*)dst = *(const uint4*)src;
}

// ---------------------------------------------------------------------------
// NT GEMM: C[M, ldc] tile = A[M,lda-stride] * Bt[N,ldb-stride]^T, bf16 MFMA.
// BN = 128: 4 waves x (4x4) 16x16 tiles.  BN = 64: 4 waves x (2x4), grid.y*2.
// Split-K via grid.z: z-th block consumes A/Bt cols [z*K, (z+1)*K) and writes
// partial C at C + z*M*ldc.  M mult of 128, K mult of 32.
// ---------------------------------------------------------------------------
template <int BN, typename AT, typename BT, typename OT>
__global__ __launch_bounds__(256, 2)
void gemm_nt(const AT* __restrict__ A, int lda, const BT* __restrict__ Bt,
             int ldb, OT* __restrict__ C, int M, int ldc, int K) {
  constexpr int MI = (BN == 128) ? 4 : 2;  // 16-row tiles per wave (rows)
  __shared__ u16 As[128][40];
  __shared__ u16 Bs[BN][40];
  const size_t koff = (size_t)blockIdx.z * K;
  A += koff;
  Bt += koff;
  C += (size_t)blockIdx.z * M * ldc;
  const int m0 = blockIdx.x * 128;
  const int n0 = blockIdx.y * BN;
  const int tid = threadIdx.x;
  const int lane = tid & 63;
  const int wv = tid >> 6;
  const int wm = (BN == 128) ? (wv & 1) : wv;
  const int wn = (BN == 128) ? (wv >> 1) : 0;
  const int lr = lane & 15;
  const int lq = lane >> 4;

  f32x4 acc[MI][4];
#pragma unroll
  for (int i = 0; i < MI; ++i)
#pragma unroll
    for (int j = 0; j < 4; ++j) acc[i][j] = (f32x4){0.f, 0.f, 0.f, 0.f};

  const int sr = tid >> 2;
  const int sc = (tid & 3) * 8;

  for (int kb = 0; kb < K; kb += 32) {
#pragma unroll
    for (int it = 0; it < 2; ++it) {
      const int r = sr + it * 64;
      stage8(&As[r][sc], &A[(size_t)(m0 + r) * lda + kb + sc]);
    }
#pragma unroll
    for (int it = 0; it < BN / 64; ++it) {
      const int r = sr + it * 64;
      stage8(&Bs[r][sc], &Bt[(size_t)(n0 + r) * ldb + kb + sc]);
    }
    __syncthreads();
    bf16x8 af[MI], bfr[4];
#pragma unroll
    for (int i = 0; i < MI; ++i)
      af[i] = *(const bf16x8*)(&As[wm * (MI * 16) + i * 16 + lr][lq * 8]);
#pragma unroll
    for (int j = 0; j < 4; ++j)
      bfr[j] = *(const bf16x8*)(&Bs[wn * 64 + j * 16 + lr][lq * 8]);
#pragma unroll
    for (int i = 0; i < MI; ++i)
#pragma unroll
      for (int j = 0; j < 4; ++j)
        acc[i][j] = __builtin_amdgcn_mfma_f32_16x16x32_bf16(af[i], bfr[j],
                                                            acc[i][j], 0, 0, 0);
    __syncthreads();
  }

#pragma unroll
  for (int i = 0; i < MI; ++i)
#pragma unroll
    for (int j = 0; j < 4; ++j) {
      const int col = n0 + wn * 64 + j * 16 + lr;
#pragma unroll
      for (int r = 0; r < 4; ++r) {
        const int row = m0 + wm * (MI * 16) + i * 16 + lq * 4 + r;
        const float v = acc[i][j][r];
        if constexpr (std::is_same_v<OT, float>) {
          C[(size_t)row * ldc + col] = v;
        } else {
          C[(size_t)row * ldc + col] = f2bu(v);
        }
      }
    }
}

// ---------------------------------------------------------------------------
// Fused gate/up GEMM + SiLU: xffn[row, c] = silu(x@Wg^T) * (x@Wu^T).
// One A tile feeds two B tiles (gate rows n0.., up rows INTER+n0..): 64 MFMA
// per 3 staged tiles.
// ---------------------------------------------------------------------------
__global__ __launch_bounds__(256, 2)
void gateup_gemm(const float* __restrict__ x, const float* __restrict__ wgu,
                 u16* __restrict__ xffn) {
  constexpr int K = 1024;
  __shared__ u16 As[128][40];
  __shared__ u16 Bg[128][40];
  __shared__ u16 Bu[128][40];
  const int m0 = blockIdx.x * 128;
  const int n0 = blockIdx.y * 128;
  const int tid = threadIdx.x;
  const int lane = tid & 63;
  const int wv = tid >> 6;
  const int wm = wv & 1, wn = wv >> 1;
  const int lr = lane & 15;
  const int lq = lane >> 4;

  f32x4 accg[4][4], accu[4][4];
#pragma unroll
  for (int i = 0; i < 4; ++i)
#pragma unroll
    for (int j = 0; j < 4; ++j) {
      accg[i][j] = (f32x4){0.f, 0.f, 0.f, 0.f};
      accu[i][j] = (f32x4){0.f, 0.f, 0.f, 0.f};
    }

  const int sr = tid >> 2;
  const int sc = (tid & 3) * 8;

  for (int kb = 0; kb < K; kb += 32) {
#pragma unroll
    for (int it = 0; it < 2; ++it) {
      const int r = sr + it * 64;
      stage8(&As[r][sc], &x[(size_t)(m0 + r) * K + kb + sc]);
      stage8(&Bg[r][sc], &wgu[(size_t)(n0 + r) * K + kb + sc]);
      stage8(&Bu[r][sc], &wgu[(size_t)(INTER + n0 + r) * K + kb + sc]);
    }
    __syncthreads();
    bf16x8 af[4], bg[4], bu[4];
#pragma unroll
    for (int i = 0; i < 4; ++i)
      af[i] = *(const bf16x8*)(&As[wm * 64 + i * 16 + lr][lq * 8]);
#pragma unroll
    for (int j = 0; j < 4; ++j) {
      bg[j] = *(const bf16x8*)(&Bg[wn * 64 + j * 16 + lr][lq * 8]);
      bu[j] = *(const bf16x8*)(&Bu[wn * 64 + j * 16 + lr][lq * 8]);
    }
#pragma unroll
    for (int i = 0; i < 4; ++i)
#pragma unroll
      for (int j = 0; j < 4; ++j) {
        accg[i][j] = __builtin_amdgcn_mfma_f32_16x16x32_bf16(af[i], bg[j],
                                                             accg[i][j], 0, 0, 0);
        accu[i][j] = __builtin_amdgcn_mfma_f32_16x16x32_bf16(af[i], bu[j],
                                                             accu[i][j], 0, 0, 0);
      }
    __syncthreads();
  }

#pragma unroll
  for (int i = 0; i < 4; ++i)
#pragma unroll
    for (int j = 0; j < 4; ++j) {
      const int col = n0 + wn * 64 + j * 16 + lr;
#pragma unroll
      for (int r = 0; r < 4; ++r) {
        const int row = m0 + wm * 64 + i * 16 + lq * 4 + r;
        const float g = accg[i][j][r];
        const float u = accu[i][j][r];
        const float s = g / (1.f + __expf(-g));
        xffn[(size_t)row * INTER + col] = f2bu(s * u);
      }
    }
}

// ---------------------------------------------------------------------------
// wm2[n, c] (128 x INTER bf16, zero-padded past 63): n = o*9+tap
// cwT[k, c] (9 x INTER, f32): conv_w[c, k] transposed
// ---------------------------------------------------------------------------
__global__ void prep_weights(const float* __restrict__ w_metric,
                             const float* __restrict__ conv_w,
                             u16* __restrict__ wm2, float* __restrict__ cwT) {
  const int c = blockIdx.x * 256 + threadIdx.x;
  const int y = blockIdx.y;
  if (y < 128) {
    float v = 0.f;
    if (y < 63) {
      const int o = y / 9, tap = y % 9;
      v = w_metric[((size_t)o * INTER + c) * 9 + tap];
    }
    wm2[(size_t)y * INTER + c] = f2bu(v);
  } else {
    const int k = y - 128;
    cwT[(size_t)k * INTER + c] = conv_w[(size_t)c * 9 + k];
  }
}

// ---------------------------------------------------------------------------
// Sum 8 split-K partials + 9 shifted taps of q -> p[0..6], add bias, emit 9
// sample records {y0, x0, ty, tx} per (b, pixel).
// ---------------------------------------------------------------------------
__global__ void offsets_kernel(const float* __restrict__ q,
                               const float* __restrict__ b_metric,
                               int4* __restrict__ samp) {
  const int t = blockIdx.x * 256 + threadIdx.x;  // 0..2047
  const int b = t >> 10, l = t & 1023;
  const int i = l >> 5, j = l & 31;
  float p[7];
#pragma unroll
  for (int o = 0; o < 7; ++o) p[o] = b_metric[o];
  for (int tap = 0; tap < 9; ++tap) {
    const int ii = i + tap / 3 - 1;
    const int jj = j + tap % 3 - 1;
    if (ii >= 0 && ii < 32 && jj >= 0 && jj < 32) {
      const size_t base = ((size_t)b * 1024 + ii * 32 + jj) * 128;
      for (int ks = 0; ks < 8; ++ks) {
        const size_t pb = (size_t)ks * 2048 * 128 + base;
#pragma unroll
        for (int o = 0; o < 7; ++o) p[o] += q[pb + o * 9 + tap];
      }
    }
  }
  const float m00 = p[0], m01 = p[1], m10 = p[2], m11 = p[3];
  const float dry = p[4], drx = p[5];
  const float sc = tanhf(p[6]);
#pragma unroll
  for (int k = 0; k < 9; ++k) {
    const float pyk = (float)(k / 3 - 1), pxk = (float)(k % 3 - 1);
    const float offy = sc * (m00 * pyk + m01 * pxk) + dry;
    const float offx = sc * (m10 * pyk + m11 * pxk) + drx;
    const float posy = (float)i + pyk + offy;
    const float posx = (float)j + pxk + offx;
    const float y0f = floorf(posy), x0f = floorf(posx);
    int4 s;
    s.x = (int)y0f;
    s.y = (int)x0f;
    s.z = __float_as_int(posy - y0f);
    s.w = __float_as_int(posx - x0f);
    samp[((size_t)b * 9 + k) * 1024 + l] = s;
  }
}

// ---------------------------------------------------------------------------
// Deformable depthwise conv, 8 channels/thread with 16B gathers.
// 720896 threads: thread -> (pix = t/352, cvec = t%352). Wave spans <=2
// pixels so samp loads are near-uniform; corners use clamped addresses with
// validity folded into the bilinear weights (no divergent loads).
// ---------------------------------------------------------------------------
__global__ __launch_bounds__(256)
void deform_kernel(const u16* __restrict__ xffn,
                   const int4* __restrict__ samp,
                   const float* __restrict__ cwT,
                   const float* __restrict__ conv_b,
                   u16* __restrict__ gridout) {
  const unsigned t = blockIdx.x * 256 + threadIdx.x;
  const unsigned pix = t / 352u;
  const unsigned cv = t - pix * 352u;
  const int c0 = cv * 8;
  const int b = pix >> 10, l = pix & 1023;

  float acc[8];
  {
    const float4 b0 = *(const float4*)(&conv_b[c0]);
    const float4 b1 = *(const float4*)(&conv_b[c0 + 4]);
    acc[0] = b0.x; acc[1] = b0.y; acc[2] = b0.z; acc[3] = b0.w;
    acc[4] = b1.x; acc[5] = b1.y; acc[6] = b1.z; acc[7] = b1.w;
  }
  const size_t pixbase = (size_t)b * 1024;
#pragma unroll
  for (int k = 0; k < 9; ++k) {
    const int4 s = samp[((size_t)b * 9 + k) * 1024 + l];
    const int y0 = s.x, x0 = s.y;
    const float ty = __int_as_float(s.z), tx = __int_as_float(s.w);
    const int y1 = y0 + 1, x1 = x0 + 1;
    const float vy0 = ((unsigned)y0 < 32u) ? 1.f : 0.f;
    const float vy1 = ((unsigned)y1 < 32u) ? 1.f : 0.f;
    const float vx0 = ((unsigned)x0 < 32u) ? 1.f : 0.f;
    const float vx1 = ((unsigned)x1 < 32u) ? 1.f : 0.f;
    const float w00 = (1.f - ty) * (1.f - tx) * vy0 * vx0;
    const float w01 = (1.f - ty) * tx * vy0 * vx1;
    const float w10 = ty * (1.f - tx) * vy1 * vx0;
    const float w11 = ty * tx * vy1 * vx1;
    const int cy0 = min(max(y0, 0), 31), cy1 = min(max(y1, 0), 31);
    const int cx0 = min(max(x0, 0), 31), cx1 = min(max(x1, 0), 31);
    const u16x8 v00 = *(const u16x8*)(&xffn[(pixbase + cy0 * 32 + cx0) * INTER + c0]);
    const u16x8 v01 = *(const u16x8*)(&xffn[(pixbase + cy0 * 32 + cx1) * INTER + c0]);
    const u16x8 v10 = *(const u16x8*)(&xffn[(pixbase + cy1 * 32 + cx0) * INTER + c0]);
    const u16x8 v11 = *(const u16x8*)(&xffn[(pixbase + cy1 * 32 + cx1) * INTER + c0]);
    const float4 cwa = *(const float4*)(&cwT[(size_t)k * INTER + c0]);
    const float4 cwb = *(const float4*)(&cwT[(size_t)k * INTER + c0 + 4]);
    const float cw[8] = {cwa.x, cwa.y, cwa.z, cwa.w, cwb.x, cwb.y, cwb.z, cwb.w};
#pragma unroll
    for (int e = 0; e < 8; ++e) {
      const float bl = w00 * bu2f(v00[e]) + w01 * bu2f(v01[e]) +
                       w10 * bu2f(v10[e]) + w11 * bu2f(v11[e]);
      acc[e] += bl * cw[e];
    }
  }
  u16 outv[8];
#pragma unroll
  for (int e = 0; e < 8; ++e) outv[e] = f2bu(acc[e]);
  *(uint4*)(&gridout[(pixbase + l) * INTER + c0]) = *(uint4*)outv;
}

// ---------------------------------------------------------------------------
extern "C" void kernel_launch(void* const* d_in, const int* in_sizes, int n_in,
                              void* d_out, int out_size, void* d_ws,
                              size_t ws_size, hipStream_t stream) {
  const float* x         = (const float*)d_in[0];
  const float* w_gate_up = (const float*)d_in[1];
  const float* w_metric  = (const float*)d_in[2];
  const float* b_metric  = (const float*)d_in[3];
  const float* conv_w    = (const float*)d_in[4];
  const float* conv_b    = (const float*)d_in[5];
  const float* w_down    = (const float*)d_in[6];
  float* out = (float*)d_out;

  // Workspace (35.6 MB peak):
  //   gridout  bf16 [0, 11.6)     written by deform, read by GEMM2
  //   q_parts  f32  [12, 20)      8 split-K partials, dead after offsets
  //   samp          [20, 20.3)
  //   wm2      bf16 [21, 21.7)
  //   cwT      f32  [22, 22.1)
  //   xffn     bf16 [24, 35.6)
  char* w = (char*)d_ws;
  u16* gridout  = (u16*)(w);
  float* q      = (float*)(w + (12u << 20));
  int4* samp    = (int4*)(w + (20u << 20));
  u16* wm2      = (u16*)(w + (21u << 20));
  float* cwT    = (float*)(w + (22u << 20));
  u16* xffn     = (u16*)(w + (24u << 20));

  // 1) x_ffn = silu(x@Wg^T) * (x@Wu^T)   (fused, 2048 x 2816 x 1024)
  gateup_gemm<<<dim3(16, 22), 256, 0, stream>>>(x, w_gate_up, xffn);
  // 2) weight repacks
  prep_weights<<<dim3(11, 137), 256, 0, stream>>>(w_metric, conv_w, wm2, cwT);
  // 3) metric conv as GEMM, split-K x8 partials (2048 x 128 x 352 each)
  gemm_nt<128, u16, u16, float><<<dim3(16, 1, 8), 256, 0, stream>>>(
      xffn, INTER, wm2, INTER, q, 2048, 128, 352);
  // 4) partial-sum + tap-sum + offsets -> sample records
  offsets_kernel<<<8, 256, 0, stream>>>(q, b_metric, samp);
  // 5) deformable depthwise conv (vectorized 8 ch/thread)
  deform_kernel<<<2816, 256, 0, stream>>>(xffn, samp, cwT, conv_b, gridout);
  // 6) out = grid_out @ w_down^T   (2048 x 1024 x 2816), BN=64 -> 256 blocks
  gemm_nt<64, u16, float, float><<<dim3(16, 16), 256, 0, stream>>>(
      gridout, INTER, w_down, INTER, out, 2048, 1024, INTER);
}

// Round 4
// 268.862 us; speedup vs baseline: 1.4402x; 1.1547x over previous
//
#include <hip/hip_runtime.h>
#include <hip/hip_bf16.h>
#include <cstdint>
#include <cstddef>
#include <type_traits>

#define INTER 2816

typedef __bf16 bf16x8 __attribute__((ext_vector_type(8)));
typedef float f32x4 __attribute__((ext_vector_type(4)));
typedef unsigned short u16x8 __attribute__((ext_vector_type(8)));
using bf16 = __hip_bfloat16;
using u16 = unsigned short;

__device__ __forceinline__ u16 f2bu(float f) {
  bf16 h = __float2bfloat16(f);
  return *reinterpret_cast<u16*>(&h);
}
__device__ __forceinline__ float bu2f(u16 u) {
  bf16 h = *reinterpret_cast<bf16*>(&u);
  return __bfloat162float(h);
}

// Stage 8 contiguous elements as bf16 (16B) into LDS.
__device__ __forceinline__ void stage8(u16* dst, const float* src) {
  const float4 a = *(const float4*)(src);
  const float4 b = *(const float4*)(src + 4);
  u16 tmp[8] = {f2bu(a.x), f2bu(a.y), f2bu(a.z), f2bu(a.w),
                f2bu(b.x), f2bu(b.y), f2bu(b.z), f2bu(b.w)};
  *(uint4*)dst = *(uint4*)tmp;
}
__device__ __forceinline__ void stage8(u16* dst, const u16* src) {
  *(uint4*)dst = *(const uint4*)src;
}

// ---------------------------------------------------------------------------
// NT GEMM, 128x128 tile, 4 waves x (4x4) 16x16x32 mfma, BK=32.
// Split-K via grid.z: block z consumes cols [z*K, (z+1)*K), writes partial C
// at C + z*M*ldc.  M mult of 128, K mult of 32.
// ---------------------------------------------------------------------------
template <typename AT, typename BT, typename OT>
__global__ __launch_bounds__(256, 2)
void gemm_nt(const AT* __restrict__ A, int lda, const BT* __restrict__ Bt,
             int ldb, OT* __restrict__ C, int M, int ldc, int K) {
  __shared__ u16 As[128][40];
  __shared__ u16 Bs[128][40];
  const size_t koff = (size_t)blockIdx.z * K;
  A += koff;
  Bt += koff;
  C += (size_t)blockIdx.z * M * ldc;
  const int m0 = blockIdx.x * 128;
  const int n0 = blockIdx.y * 128;
  const int tid = threadIdx.x;
  const int lane = tid & 63;
  const int wv = tid >> 6;
  const int wm = wv & 1, wn = wv >> 1;
  const int lr = lane & 15;
  const int lq = lane >> 4;

  f32x4 acc[4][4];
#pragma unroll
  for (int i = 0; i < 4; ++i)
#pragma unroll
    for (int j = 0; j < 4; ++j) acc[i][j] = (f32x4){0.f, 0.f, 0.f, 0.f};

  const int sr = tid >> 2;
  const int sc = (tid & 3) * 8;

  for (int kb = 0; kb < K; kb += 32) {
#pragma unroll
    for (int it = 0; it < 2; ++it) {
      const int r = sr + it * 64;
      stage8(&As[r][sc], &A[(size_t)(m0 + r) * lda + kb + sc]);
      stage8(&Bs[r][sc], &Bt[(size_t)(n0 + r) * ldb + kb + sc]);
    }
    __syncthreads();
    bf16x8 af[4], bfr[4];
#pragma unroll
    for (int i = 0; i < 4; ++i)
      af[i] = *(const bf16x8*)(&As[wm * 64 + i * 16 + lr][lq * 8]);
#pragma unroll
    for (int j = 0; j < 4; ++j)
      bfr[j] = *(const bf16x8*)(&Bs[wn * 64 + j * 16 + lr][lq * 8]);
#pragma unroll
    for (int i = 0; i < 4; ++i)
#pragma unroll
      for (int j = 0; j < 4; ++j)
        acc[i][j] = __builtin_amdgcn_mfma_f32_16x16x32_bf16(af[i], bfr[j],
                                                            acc[i][j], 0, 0, 0);
    __syncthreads();
  }

#pragma unroll
  for (int i = 0; i < 4; ++i)
#pragma unroll
    for (int j = 0; j < 4; ++j) {
      const int col = n0 + wn * 64 + j * 16 + lr;
#pragma unroll
      for (int r = 0; r < 4; ++r) {
        const int row = m0 + wm * 64 + i * 16 + lq * 4 + r;
        const float v = acc[i][j][r];
        if constexpr (std::is_same_v<OT, float>) {
          C[(size_t)row * ldc + col] = v;
        } else {
          C[(size_t)row * ldc + col] = f2bu(v);
        }
      }
    }
}

// ---------------------------------------------------------------------------
// out[i] = sum of 4 split-K partials (f32), float4-vectorized.
// ---------------------------------------------------------------------------
__global__ void reduce4(const float* __restrict__ q2, float* __restrict__ out) {
  const size_t i = ((size_t)blockIdx.x * 256 + threadIdx.x) * 4;
  const size_t S = (size_t)2048 * 1024;
  float4 a = *(const float4*)(q2 + i);
  const float4 b = *(const float4*)(q2 + S + i);
  const float4 c = *(const float4*)(q2 + 2 * S + i);
  const float4 d = *(const float4*)(q2 + 3 * S + i);
  a.x += b.x + c.x + d.x;
  a.y += b.y + c.y + d.y;
  a.z += b.z + c.z + d.z;
  a.w += b.w + c.w + d.w;
  *(float4*)(out + i) = a;
}

// ---------------------------------------------------------------------------
// Fused gate/up GEMM + SiLU, 128x64 tile (64 gate cols + 64 up cols).
// Grid 16 x 44 = 704 blocks (2.75 blocks/CU). 4 waves = 2(m) x 2(n);
// wave tile 64 rows x 32 cols of each of gate/up: 16 MFMA / 4 stages.
// ---------------------------------------------------------------------------
__global__ __launch_bounds__(256, 2)
void gateup_gemm(const float* __restrict__ x, const float* __restrict__ wgu,
                 u16* __restrict__ xffn) {
  constexpr int K = 1024;
  __shared__ u16 As[128][40];
  __shared__ u16 Bg[64][40];
  __shared__ u16 Bu[64][40];
  const int m0 = blockIdx.x * 128;
  const int n0 = blockIdx.y * 64;
  const int tid = threadIdx.x;
  const int lane = tid & 63;
  const int wv = tid >> 6;
  const int wm = wv & 1, wn = wv >> 1;
  const int lr = lane & 15;
  const int lq = lane >> 4;

  f32x4 accg[4][2], accu[4][2];
#pragma unroll
  for (int i = 0; i < 4; ++i)
#pragma unroll
    for (int j = 0; j < 2; ++j) {
      accg[i][j] = (f32x4){0.f, 0.f, 0.f, 0.f};
      accu[i][j] = (f32x4){0.f, 0.f, 0.f, 0.f};
    }

  const int sr = tid >> 2;       // 0..63
  const int sc = (tid & 3) * 8;

  for (int kb = 0; kb < K; kb += 32) {
#pragma unroll
    for (int it = 0; it < 2; ++it) {
      const int r = sr + it * 64;
      stage8(&As[r][sc], &x[(size_t)(m0 + r) * K + kb + sc]);
    }
    stage8(&Bg[sr][sc], &wgu[(size_t)(n0 + sr) * K + kb + sc]);
    stage8(&Bu[sr][sc], &wgu[(size_t)(INTER + n0 + sr) * K + kb + sc]);
    __syncthreads();
    bf16x8 af[4], bg[2], bu[2];
#pragma unroll
    for (int i = 0; i < 4; ++i)
      af[i] = *(const bf16x8*)(&As[wm * 64 + i * 16 + lr][lq * 8]);
#pragma unroll
    for (int j = 0; j < 2; ++j) {
      bg[j] = *(const bf16x8*)(&Bg[wn * 32 + j * 16 + lr][lq * 8]);
      bu[j] = *(const bf16x8*)(&Bu[wn * 32 + j * 16 + lr][lq * 8]);
    }
#pragma unroll
    for (int i = 0; i < 4; ++i)
#pragma unroll
      for (int j = 0; j < 2; ++j) {
        accg[i][j] = __builtin_amdgcn_mfma_f32_16x16x32_bf16(af[i], bg[j],
                                                             accg[i][j], 0, 0, 0);
        accu[i][j] = __builtin_amdgcn_mfma_f32_16x16x32_bf16(af[i], bu[j],
                                                             accu[i][j], 0, 0, 0);
      }
    __syncthreads();
  }

#pragma unroll
  for (int i = 0; i < 4; ++i)
#pragma unroll
    for (int j = 0; j < 2; ++j) {
      const int col = n0 + wn * 32 + j * 16 + lr;
#pragma unroll
      for (int r = 0; r < 4; ++r) {
        const int row = m0 + wm * 64 + i * 16 + lq * 4 + r;
        const float g = accg[i][j][r];
        const float u = accu[i][j][r];
        const float s = g / (1.f + __expf(-g));
        xffn[(size_t)row * INTER + col] = f2bu(s * u);
      }
    }
}

// ---------------------------------------------------------------------------
// wm2[n, c] (128 x INTER bf16, zero-padded past 63): n = o*9+tap
// cwT[k, c] (9 x INTER, f32): conv_w[c, k] transposed
// ---------------------------------------------------------------------------
__global__ void prep_weights(const float* __restrict__ w_metric,
                             const float* __restrict__ conv_w,
                             u16* __restrict__ wm2, float* __restrict__ cwT) {
  const int c = blockIdx.x * 256 + threadIdx.x;
  const int y = blockIdx.y;
  if (y < 128) {
    float v = 0.f;
    if (y < 63) {
      const int o = y / 9, tap = y % 9;
      v = w_metric[((size_t)o * INTER + c) * 9 + tap];
    }
    wm2[(size_t)y * INTER + c] = f2bu(v);
  } else {
    const int k = y - 128;
    cwT[(size_t)k * INTER + c] = conv_w[(size_t)c * 9 + k];
  }
}

// ---------------------------------------------------------------------------
// Sum 8 split-K partials + 9 shifted taps of q -> p[0..6], add bias, emit 9
// sample records {y0, x0, ty, tx} per (b, pixel).
// ---------------------------------------------------------------------------
__global__ void offsets_kernel(const float* __restrict__ q,
                               const float* __restrict__ b_metric,
                               int4* __restrict__ samp) {
  const int t = blockIdx.x * 256 + threadIdx.x;  // 0..2047
  const int b = t >> 10, l = t & 1023;
  const int i = l >> 5, j = l & 31;
  float p[7];
#pragma unroll
  for (int o = 0; o < 7; ++o) p[o] = b_metric[o];
  for (int tap = 0; tap < 9; ++tap) {
    const int ii = i + tap / 3 - 1;
    const int jj = j + tap % 3 - 1;
    if (ii >= 0 && ii < 32 && jj >= 0 && jj < 32) {
      const size_t base = ((size_t)b * 1024 + ii * 32 + jj) * 128;
      for (int ks = 0; ks < 8; ++ks) {
        const size_t pb = (size_t)ks * 2048 * 128 + base;
#pragma unroll
        for (int o = 0; o < 7; ++o) p[o] += q[pb + o * 9 + tap];
      }
    }
  }
  const float m00 = p[0], m01 = p[1], m10 = p[2], m11 = p[3];
  const float dry = p[4], drx = p[5];
  const float sc = tanhf(p[6]);
#pragma unroll
  for (int k = 0; k < 9; ++k) {
    const float pyk = (float)(k / 3 - 1), pxk = (float)(k % 3 - 1);
    const float offy = sc * (m00 * pyk + m01 * pxk) + dry;
    const float offx = sc * (m10 * pyk + m11 * pxk) + drx;
    const float posy = (float)i + pyk + offy;
    const float posx = (float)j + pxk + offx;
    const float y0f = floorf(posy), x0f = floorf(posx);
    int4 s;
    s.x = (int)y0f;
    s.y = (int)x0f;
    s.z = __float_as_int(posy - y0f);
    s.w = __float_as_int(posx - x0f);
    samp[((size_t)b * 9 + k) * 1024 + l] = s;
  }
}

// ---------------------------------------------------------------------------
// Deformable depthwise conv, 8 channels/thread with 16B gathers.
// ---------------------------------------------------------------------------
__global__ __launch_bounds__(256)
void deform_kernel(const u16* __restrict__ xffn,
                   const int4* __restrict__ samp,
                   const float* __restrict__ cwT,
                   const float* __restrict__ conv_b,
                   u16* __restrict__ gridout) {
  const unsigned t = blockIdx.x * 256 + threadIdx.x;
  const unsigned pix = t / 352u;
  const unsigned cv = t - pix * 352u;
  const int c0 = cv * 8;
  const int b = pix >> 10, l = pix & 1023;

  float acc[8];
  {
    const float4 b0 = *(const float4*)(&conv_b[c0]);
    const float4 b1 = *(const float4*)(&conv_b[c0 + 4]);
    acc[0] = b0.x; acc[1] = b0.y; acc[2] = b0.z; acc[3] = b0.w;
    acc[4] = b1.x; acc[5] = b1.y; acc[6] = b1.z; acc[7] = b1.w;
  }
  const size_t pixbase = (size_t)b * 1024;
#pragma unroll
  for (int k = 0; k < 9; ++k) {
    const int4 s = samp[((size_t)b * 9 + k) * 1024 + l];
    const int y0 = s.x, x0 = s.y;
    const float ty = __int_as_float(s.z), tx = __int_as_float(s.w);
    const int y1 = y0 + 1, x1 = x0 + 1;
    const float vy0 = ((unsigned)y0 < 32u) ? 1.f : 0.f;
    const float vy1 = ((unsigned)y1 < 32u) ? 1.f : 0.f;
    const float vx0 = ((unsigned)x0 < 32u) ? 1.f : 0.f;
    const float vx1 = ((unsigned)x1 < 32u) ? 1.f : 0.f;
    const float w00 = (1.f - ty) * (1.f - tx) * vy0 * vx0;
    const float w01 = (1.f - ty) * tx * vy0 * vx1;
    const float w10 = ty * (1.f - tx) * vy1 * vx0;
    const float w11 = ty * tx * vy1 * vx1;
    const int cy0 = min(max(y0, 0), 31), cy1 = min(max(y1, 0), 31);
    const int cx0 = min(max(x0, 0), 31), cx1 = min(max(x1, 0), 31);
    const u16x8 v00 = *(const u16x8*)(&xffn[(pixbase + cy0 * 32 + cx0) * INTER + c0]);
    const u16x8 v01 = *(const u16x8*)(&xffn[(pixbase + cy0 * 32 + cx1) * INTER + c0]);
    const u16x8 v10 = *(const u16x8*)(&xffn[(pixbase + cy1 * 32 + cx0) * INTER + c0]);
    const u16x8 v11 = *(const u16x8*)(&xffn[(pixbase + cy1 * 32 + cx1) * INTER + c0]);
    const float4 cwa = *(const float4*)(&cwT[(size_t)k * INTER + c0]);
    const float4 cwb = *(const float4*)(&cwT[(size_t)k * INTER + c0 + 4]);
    const float cw[8] = {cwa.x, cwa.y, cwa.z, cwa.w, cwb.x, cwb.y, cwb.z, cwb.w};
#pragma unroll
    for (int e = 0; e < 8; ++e) {
      const float bl = w00 * bu2f(v00[e]) + w01 * bu2f(v01[e]) +
                       w10 * bu2f(v10[e]) + w11 * bu2f(v11[e]);
      acc[e] += bl * cw[e];
    }
  }
  u16 outv[8];
#pragma unroll
  for (int e = 0; e < 8; ++e) outv[e] = f2bu(acc[e]);
  *(uint4*)(&gridout[(pixbase + l) * INTER + c0]) = *(uint4*)outv;
}

// ---------------------------------------------------------------------------
extern "C" void kernel_launch(void* const* d_in, const int* in_sizes, int n_in,
                              void* d_out, int out_size, void* d_ws,
                              size_t ws_size, hipStream_t stream) {
  const float* x         = (const float*)d_in[0];
  const float* w_gate_up = (const float*)d_in[1];
  const float* w_metric  = (const float*)d_in[2];
  const float* b_metric  = (const float*)d_in[3];
  const float* conv_w    = (const float*)d_in[4];
  const float* conv_b    = (const float*)d_in[5];
  const float* w_down    = (const float*)d_in[6];
  float* out = (float*)d_out;

  // Workspace (44 MB peak):
  //   gridout  bf16 [0, 11.6)   written by deform, read by GEMM2
  //   q_conv   f32  [12, 20)    8 conv split-K partials, dead after offsets
  //   samp          [20, 20.3)  dead after deform
  //   wm2      bf16 [21, 21.7)  dead after conv GEMM
  //   cwT      f32  [22, 22.1)  dead after deform
  //   xffn     bf16 [24, 35.6)  dead after deform
  //   q2       f32  [12, 44)    4 GEMM2 split-K partials — overlays the
  //                             dead q_conv/samp/wm2/cwT/xffn regions
  char* w = (char*)d_ws;
  u16* gridout  = (u16*)(w);
  float* q      = (float*)(w + (12u << 20));
  int4* samp    = (int4*)(w + (20u << 20));
  u16* wm2      = (u16*)(w + (21u << 20));
  float* cwT    = (float*)(w + (22u << 20));
  u16* xffn     = (u16*)(w + (24u << 20));
  float* q2     = (float*)(w + (12u << 20));

  // 1) x_ffn = silu(x@Wg^T) * (x@Wu^T)   (fused, 128x64 tiles, 704 blocks)
  gateup_gemm<<<dim3(16, 44), 256, 0, stream>>>(x, w_gate_up, xffn);
  // 2) weight repacks
  prep_weights<<<dim3(11, 137), 256, 0, stream>>>(w_metric, conv_w, wm2, cwT);
  // 3) metric conv as GEMM, split-K x8 partials (2048 x 128 x 352 each)
  gemm_nt<u16, u16, float><<<dim3(16, 1, 8), 256, 0, stream>>>(
      xffn, INTER, wm2, INTER, q, 2048, 128, 352);
  // 4) partial-sum + tap-sum + offsets -> sample records
  offsets_kernel<<<8, 256, 0, stream>>>(q, b_metric, samp);
  // 5) deformable depthwise conv (vectorized 8 ch/thread)
  deform_kernel<<<2816, 256, 0, stream>>>(xffn, samp, cwT, conv_b, gridout);
  // 6) GEMM2 split-K x4: partials q2[z] = gridout @ w_down^T (K=704 slices)
  gemm_nt<u16, float, float><<<dim3(16, 8, 4), 256, 0, stream>>>(
      gridout, INTER, w_down, INTER, q2, 2048, 1024, 704);
  // 7) out = sum of 4 partials
  reduce4<<<2048, 256, 0, stream>>>(q2, out);
}

// Round 5
// 221.008 us; speedup vs baseline: 1.7521x; 1.2165x over previous
//
#include <hip/hip_runtime.h>
#include <hip/hip_bf16.h>
#include <cstdint>
#include <cstddef>
#include <type_traits>

#define INTER 2816

typedef __bf16 bf16x8 __attribute__((ext_vector_type(8)));
typedef float f32x4 __attribute__((ext_vector_type(4)));
typedef unsigned short u16x8 __attribute__((ext_vector_type(8)));
using bf16 = __hip_bfloat16;
using u16 = unsigned short;

__device__ __forceinline__ u16 f2bu(float f) {
  bf16 h = __float2bfloat16(f);
  return *reinterpret_cast<u16*>(&h);
}
__device__ __forceinline__ float bu2f(u16 u) {
  bf16 h = *reinterpret_cast<bf16*>(&u);
  return __bfloat162float(h);
}

// Stage 8 contiguous elements as bf16 (16B).
__device__ __forceinline__ void stage8(u16* dst, const float* src) {
  const float4 a = *(const float4*)(src);
  const float4 b = *(const float4*)(src + 4);
  u16 tmp[8] = {f2bu(a.x), f2bu(a.y), f2bu(a.z), f2bu(a.w),
                f2bu(b.x), f2bu(b.y), f2bu(b.z), f2bu(b.w)};
  *(uint4*)dst = *(uint4*)tmp;
}
__device__ __forceinline__ void stage8(u16* dst, const u16* src) {
  *(uint4*)dst = *(const uint4*)src;
}

// ---------------------------------------------------------------------------
// One-shot f32 -> bf16 conversion of x, w_gate_up, w_down (8 elems/thread).
// ---------------------------------------------------------------------------
__global__ __launch_bounds__(256)
void convert_bf16(const float* __restrict__ x, const float* __restrict__ wgu,
                  const float* __restrict__ wd, u16* __restrict__ xbf,
                  u16* __restrict__ wgubf, u16* __restrict__ wdbf) {
  constexpr size_t S0 = (size_t)2048 * 1024;
  constexpr size_t S1 = (size_t)5632 * 1024;
  const size_t e0 = ((size_t)blockIdx.x * 256 + threadIdx.x) * 8;
  const float* src;
  u16* dst;
  size_t off;
  if (e0 < S0) {
    src = x; dst = xbf; off = e0;
  } else if (e0 < S0 + S1) {
    src = wgu; dst = wgubf; off = e0 - S0;
  } else {
    src = wd; dst = wdbf; off = e0 - S0 - S1;
  }
  stage8(dst + off, src + off);
}

// ---------------------------------------------------------------------------
// NT GEMM, 128x128 tile, 4 waves x (4x4) 16x16x32 mfma, BK=32.
// Split-K via grid.z: block z consumes cols [z*K, (z+1)*K), writes partial C
// at C + z*M*ldc.  M mult of 128, K mult of 32.
// ---------------------------------------------------------------------------
template <typename OT>
__global__ __launch_bounds__(256, 2)
void gemm_nt(const u16* __restrict__ A, int lda, const u16* __restrict__ Bt,
             int ldb, OT* __restrict__ C, int M, int ldc, int K) {
  __shared__ u16 As[128][40];
  __shared__ u16 Bs[128][40];
  const size_t koff = (size_t)blockIdx.z * K;
  A += koff;
  Bt += koff;
  C += (size_t)blockIdx.z * M * ldc;
  const int m0 = blockIdx.x * 128;
  const int n0 = blockIdx.y * 128;
  const int tid = threadIdx.x;
  const int lane = tid & 63;
  const int wv = tid >> 6;
  const int wm = wv & 1, wn = wv >> 1;
  const int lr = lane & 15;
  const int lq = lane >> 4;

  f32x4 acc[4][4];
#pragma unroll
  for (int i = 0; i < 4; ++i)
#pragma unroll
    for (int j = 0; j < 4; ++j) acc[i][j] = (f32x4){0.f, 0.f, 0.f, 0.f};

  const int sr = tid >> 2;
  const int sc = (tid & 3) * 8;

  for (int kb = 0; kb < K; kb += 32) {
#pragma unroll
    for (int it = 0; it < 2; ++it) {
      const int r = sr + it * 64;
      stage8(&As[r][sc], &A[(size_t)(m0 + r) * lda + kb + sc]);
      stage8(&Bs[r][sc], &Bt[(size_t)(n0 + r) * ldb + kb + sc]);
    }
    __syncthreads();
    bf16x8 af[4], bfr[4];
#pragma unroll
    for (int i = 0; i < 4; ++i)
      af[i] = *(const bf16x8*)(&As[wm * 64 + i * 16 + lr][lq * 8]);
#pragma unroll
    for (int j = 0; j < 4; ++j)
      bfr[j] = *(const bf16x8*)(&Bs[wn * 64 + j * 16 + lr][lq * 8]);
#pragma unroll
    for (int i = 0; i < 4; ++i)
#pragma unroll
      for (int j = 0; j < 4; ++j)
        acc[i][j] = __builtin_amdgcn_mfma_f32_16x16x32_bf16(af[i], bfr[j],
                                                            acc[i][j], 0, 0, 0);
    __syncthreads();
  }

#pragma unroll
  for (int i = 0; i < 4; ++i)
#pragma unroll
    for (int j = 0; j < 4; ++j) {
      const int col = n0 + wn * 64 + j * 16 + lr;
#pragma unroll
      for (int r = 0; r < 4; ++r) {
        const int row = m0 + wm * 64 + i * 16 + lq * 4 + r;
        const float v = acc[i][j][r];
        if constexpr (std::is_same_v<OT, float>) {
          C[(size_t)row * ldc + col] = v;
        } else {
          C[(size_t)row * ldc + col] = f2bu(v);
        }
      }
    }
}

// ---------------------------------------------------------------------------
// out[i] = sum of 4 split-K partials (f32), float4-vectorized.
// ---------------------------------------------------------------------------
__global__ void reduce4(const float* __restrict__ q2, float* __restrict__ out) {
  const size_t i = ((size_t)blockIdx.x * 256 + threadIdx.x) * 4;
  const size_t S = (size_t)2048 * 1024;
  float4 a = *(const float4*)(q2 + i);
  const float4 b = *(const float4*)(q2 + S + i);
  const float4 c = *(const float4*)(q2 + 2 * S + i);
  const float4 d = *(const float4*)(q2 + 3 * S + i);
  a.x += b.x + c.x + d.x;
  a.y += b.y + c.y + d.y;
  a.z += b.z + c.z + d.z;
  a.w += b.w + c.w + d.w;
  *(float4*)(out + i) = a;
}

// ---------------------------------------------------------------------------
// Fused gate/up GEMM + SiLU, 128x64 tile (64 gate cols + 64 up cols), bf16 in.
// Grid 16 x 44 = 704 blocks. 4 waves = 2(m) x 2(n).
// ---------------------------------------------------------------------------
__global__ __launch_bounds__(256, 2)
void gateup_gemm(const u16* __restrict__ x, const u16* __restrict__ wgu,
                 u16* __restrict__ xffn) {
  constexpr int K = 1024;
  __shared__ u16 As[128][40];
  __shared__ u16 Bg[64][40];
  __shared__ u16 Bu[64][40];
  const int m0 = blockIdx.x * 128;
  const int n0 = blockIdx.y * 64;
  const int tid = threadIdx.x;
  const int lane = tid & 63;
  const int wv = tid >> 6;
  const int wm = wv & 1, wn = wv >> 1;
  const int lr = lane & 15;
  const int lq = lane >> 4;

  f32x4 accg[4][2], accu[4][2];
#pragma unroll
  for (int i = 0; i < 4; ++i)
#pragma unroll
    for (int j = 0; j < 2; ++j) {
      accg[i][j] = (f32x4){0.f, 0.f, 0.f, 0.f};
      accu[i][j] = (f32x4){0.f, 0.f, 0.f, 0.f};
    }

  const int sr = tid >> 2;
  const int sc = (tid & 3) * 8;

  for (int kb = 0; kb < K; kb += 32) {
#pragma unroll
    for (int it = 0; it < 2; ++it) {
      const int r = sr + it * 64;
      stage8(&As[r][sc], &x[(size_t)(m0 + r) * K + kb + sc]);
    }
    stage8(&Bg[sr][sc], &wgu[(size_t)(n0 + sr) * K + kb + sc]);
    stage8(&Bu[sr][sc], &wgu[(size_t)(INTER + n0 + sr) * K + kb + sc]);
    __syncthreads();
    bf16x8 af[4], bg[2], bu[2];
#pragma unroll
    for (int i = 0; i < 4; ++i)
      af[i] = *(const bf16x8*)(&As[wm * 64 + i * 16 + lr][lq * 8]);
#pragma unroll
    for (int j = 0; j < 2; ++j) {
      bg[j] = *(const bf16x8*)(&Bg[wn * 32 + j * 16 + lr][lq * 8]);
      bu[j] = *(const bf16x8*)(&Bu[wn * 32 + j * 16 + lr][lq * 8]);
    }
#pragma unroll
    for (int i = 0; i < 4; ++i)
#pragma unroll
      for (int j = 0; j < 2; ++j) {
        accg[i][j] = __builtin_amdgcn_mfma_f32_16x16x32_bf16(af[i], bg[j],
                                                             accg[i][j], 0, 0, 0);
        accu[i][j] = __builtin_amdgcn_mfma_f32_16x16x32_bf16(af[i], bu[j],
                                                             accu[i][j], 0, 0, 0);
      }
    __syncthreads();
  }

#pragma unroll
  for (int i = 0; i < 4; ++i)
#pragma unroll
    for (int j = 0; j < 2; ++j) {
      const int col = n0 + wn * 32 + j * 16 + lr;
#pragma unroll
      for (int r = 0; r < 4; ++r) {
        const int row = m0 + wm * 64 + i * 16 + lq * 4 + r;
        const float g = accg[i][j][r];
        const float u = accu[i][j][r];
        const float s = g / (1.f + __expf(-g));
        xffn[(size_t)row * INTER + col] = f2bu(s * u);
      }
    }
}

// ---------------------------------------------------------------------------
// wm2[n, c] (128 x INTER bf16, zero-padded past 63): n = o*9+tap
// cwT[k, c] (9 x INTER, f32): conv_w[c, k] transposed
// ---------------------------------------------------------------------------
__global__ void prep_weights(const float* __restrict__ w_metric,
                             const float* __restrict__ conv_w,
                             u16* __restrict__ wm2, float* __restrict__ cwT) {
  const int c = blockIdx.x * 256 + threadIdx.x;
  const int y = blockIdx.y;
  if (y < 128) {
    float v = 0.f;
    if (y < 63) {
      const int o = y / 9, tap = y % 9;
      v = w_metric[((size_t)o * INTER + c) * 9 + tap];
    }
    wm2[(size_t)y * INTER + c] = f2bu(v);
  } else {
    const int k = y - 128;
    cwT[(size_t)k * INTER + c] = conv_w[(size_t)c * 9 + k];
  }
}

// ---------------------------------------------------------------------------
// Fused: sum 8 split-K partials of q + 9-tap shifted sum + offsets + sample
// records. One block (1 wave) per 64 pixels; cooperative coalesced LDS load
// of the 130-pixel neighbor window (64 cols), then per-lane tap-sum from LDS
// (row stride 65 words -> conflict-free).
// ---------------------------------------------------------------------------
__global__ __launch_bounds__(64)
void offsets_fused(const float* __restrict__ q,   // [8][2048][128]
                   const float* __restrict__ b_metric,
                   int4* __restrict__ samp) {
  __shared__ float lds[130 * 65];
  const int chunk = blockIdx.x;      // 0..31
  const int b = chunk >> 4;
  const int c0 = (chunk & 15) * 64;  // batch-local first pixel of this block
  const int t = threadIdx.x;         // 0..63

  // Load 130 rows x 64 cols, summing the 8 split-K partials. float4, coalesced.
  for (int v = t; v < 130 * 16; v += 64) {
    const int row = v >> 4;
    const int c4 = (v & 15) * 4;
    int pg = c0 - 33 + row;
    pg = min(max(pg, 0), 1023);
    const float* src = q + ((size_t)b * 1024 + pg) * 128 + c4;
    float4 s = *(const float4*)(src);
#pragma unroll
    for (int ks = 1; ks < 8; ++ks) {
      const float4 vv = *(const float4*)(src + (size_t)ks * 2048 * 128);
      s.x += vv.x; s.y += vv.y; s.z += vv.z; s.w += vv.w;
    }
    float* d = &lds[row * 65 + c4];
    d[0] = s.x; d[1] = s.y; d[2] = s.z; d[3] = s.w;
  }
  __syncthreads();

  const int pix = c0 + t;
  const int i = pix >> 5, j = pix & 31;
  float p[7];
#pragma unroll
  for (int o = 0; o < 7; ++o) p[o] = b_metric[o];
#pragma unroll
  for (int tap = 0; tap < 9; ++tap) {
    const int dy = tap / 3 - 1, dx = tap % 3 - 1;
    const int ii = i + dy, jj = j + dx;
    if ((unsigned)ii < 32u && (unsigned)jj < 32u) {
      const float* r = &lds[(t + 33 + dy * 32 + dx) * 65 + tap];
#pragma unroll
      for (int o = 0; o < 7; ++o) p[o] += r[o * 9];
    }
  }
  const float m00 = p[0], m01 = p[1], m10 = p[2], m11 = p[3];
  const float dry = p[4], drx = p[5];
  const float sc = tanhf(p[6]);
#pragma unroll
  for (int k = 0; k < 9; ++k) {
    const float pyk = (float)(k / 3 - 1), pxk = (float)(k % 3 - 1);
    const float offy = sc * (m00 * pyk + m01 * pxk) + dry;
    const float offx = sc * (m10 * pyk + m11 * pxk) + drx;
    const float posy = (float)i + pyk + offy;
    const float posx = (float)j + pxk + offx;
    const float y0f = floorf(posy), x0f = floorf(posx);
    int4 s;
    s.x = (int)y0f;
    s.y = (int)x0f;
    s.z = __float_as_int(posy - y0f);
    s.w = __float_as_int(posx - x0f);
    samp[((size_t)b * 9 + k) * 1024 + pix] = s;
  }
}

// ---------------------------------------------------------------------------
// Deformable depthwise conv, 8 channels/thread with 16B gathers.
// ---------------------------------------------------------------------------
__global__ __launch_bounds__(256)
void deform_kernel(const u16* __restrict__ xffn,
                   const int4* __restrict__ samp,
                   const float* __restrict__ cwT,
                   const float* __restrict__ conv_b,
                   u16* __restrict__ gridout) {
  const unsigned t = blockIdx.x * 256 + threadIdx.x;
  const unsigned pix = t / 352u;
  const unsigned cv = t - pix * 352u;
  const int c0 = cv * 8;
  const int b = pix >> 10, l = pix & 1023;

  float acc[8];
  {
    const float4 b0 = *(const float4*)(&conv_b[c0]);
    const float4 b1 = *(const float4*)(&conv_b[c0 + 4]);
    acc[0] = b0.x; acc[1] = b0.y; acc[2] = b0.z; acc[3] = b0.w;
    acc[4] = b1.x; acc[5] = b1.y; acc[6] = b1.z; acc[7] = b1.w;
  }
  const size_t pixbase = (size_t)b * 1024;
#pragma unroll
  for (int k = 0; k < 9; ++k) {
    const int4 s = samp[((size_t)b * 9 + k) * 1024 + l];
    const int y0 = s.x, x0 = s.y;
    const float ty = __int_as_float(s.z), tx = __int_as_float(s.w);
    const int y1 = y0 + 1, x1 = x0 + 1;
    const float vy0 = ((unsigned)y0 < 32u) ? 1.f : 0.f;
    const float vy1 = ((unsigned)y1 < 32u) ? 1.f : 0.f;
    const float vx0 = ((unsigned)x0 < 32u) ? 1.f : 0.f;
    const float vx1 = ((unsigned)x1 < 32u) ? 1.f : 0.f;
    const float w00 = (1.f - ty) * (1.f - tx) * vy0 * vx0;
    const float w01 = (1.f - ty) * tx * vy0 * vx1;
    const float w10 = ty * (1.f - tx) * vy1 * vx0;
    const float w11 = ty * tx * vy1 * vx1;
    const int cy0 = min(max(y0, 0), 31), cy1 = min(max(y1, 0), 31);
    const int cx0 = min(max(x0, 0), 31), cx1 = min(max(x1, 0), 31);
    const u16x8 v00 = *(const u16x8*)(&xffn[(pixbase + cy0 * 32 + cx0) * INTER + c0]);
    const u16x8 v01 = *(const u16x8*)(&xffn[(pixbase + cy0 * 32 + cx1) * INTER + c0]);
    const u16x8 v10 = *(const u16x8*)(&xffn[(pixbase + cy1 * 32 + cx0) * INTER + c0]);
    const u16x8 v11 = *(const u16x8*)(&xffn[(pixbase + cy1 * 32 + cx1) * INTER + c0]);
    const float4 cwa = *(const float4*)(&cwT[(size_t)k * INTER + c0]);
    const float4 cwb = *(const float4*)(&cwT[(size_t)k * INTER + c0 + 4]);
    const float cw[8] = {cwa.x, cwa.y, cwa.z, cwa.w, cwb.x, cwb.y, cwb.z, cwb.w};
#pragma unroll
    for (int e = 0; e < 8; ++e) {
      const float bl = w00 * bu2f(v00[e]) + w01 * bu2f(v01[e]) +
                       w10 * bu2f(v10[e]) + w11 * bu2f(v11[e]);
      acc[e] += bl * cw[e];
    }
  }
  u16 outv[8];
#pragma unroll
  for (int e = 0; e < 8; ++e) outv[e] = f2bu(acc[e]);
  *(uint4*)(&gridout[(pixbase + l) * INTER + c0]) = *(uint4*)outv;
}

// ---------------------------------------------------------------------------
extern "C" void kernel_launch(void* const* d_in, const int* in_sizes, int n_in,
                              void* d_out, int out_size, void* d_ws,
                              size_t ws_size, hipStream_t stream) {
  const float* x         = (const float*)d_in[0];
  const float* w_gate_up = (const float*)d_in[1];
  const float* w_metric  = (const float*)d_in[2];
  const float* b_metric  = (const float*)d_in[3];
  const float* conv_w    = (const float*)d_in[4];
  const float* conv_b    = (const float*)d_in[5];
  const float* w_down    = (const float*)d_in[6];
  float* out = (float*)d_out;

  // Workspace (~50 MB peak). Lifetimes:
  //   gridout [0, 11.53)  bf16   step 6 -> 7
  //   q2      [12, 44)    f32    step 7 -> 8; region shared (earlier steps):
  //     xffn   [12, 23.6)  bf16  step 2 -> 6
  //     xbf    [24, 28.2)  bf16  step 1 -> 2
  //     wgubf  [28.25, 39.8) bf16 step 1 -> 2
  //     q_conv [28.25, 36.25) f32 step 4 -> 5 (overlays dead wgubf)
  //     wm2    [40, 40.72) bf16  step 3 -> 4
  //     cwT    [41, 41.11) f32   step 3 -> 6
  //     samp   [42, 42.3)  int4  step 5 -> 6
  //   wdbf    [44, 49.8)  bf16   step 1 -> 7
  char* w = (char*)d_ws;
  u16* gridout  = (u16*)(w);
  float* q2     = (float*)(w + (12u << 20));
  u16* xffn     = (u16*)(w + (12u << 20));
  u16* xbf      = (u16*)(w + (24u << 20));
  u16* wgubf    = (u16*)(w + (28u << 20) + (256u << 10));
  float* q_conv = (float*)(w + (28u << 20) + (256u << 10));
  u16* wm2      = (u16*)(w + (40u << 20));
  float* cwT    = (float*)(w + (41u << 20));
  int4* samp    = (int4*)(w + (42u << 20));
  u16* wdbf     = (u16*)(w + (44u << 20));

  // 1) one-shot bf16 conversion of x, w_gate_up, w_down
  convert_bf16<<<5248, 256, 0, stream>>>(x, w_gate_up, w_down,
                                         xbf, wgubf, wdbf);
  // 2) x_ffn = silu(x@Wg^T) * (x@Wu^T)   (128x64 tiles, 704 blocks)
  gateup_gemm<<<dim3(16, 44), 256, 0, stream>>>(xbf, wgubf, xffn);
  // 3) weight repacks
  prep_weights<<<dim3(11, 137), 256, 0, stream>>>(w_metric, conv_w, wm2, cwT);
  // 4) metric conv as GEMM, split-K x8 partials (2048 x 128 x 352 each)
  gemm_nt<float><<<dim3(16, 1, 8), 256, 0, stream>>>(
      xffn, INTER, wm2, INTER, q_conv, 2048, 128, 352);
  // 5) fused partial-sum + tap-sum + offsets -> sample records
  offsets_fused<<<32, 64, 0, stream>>>(q_conv, b_metric, samp);
  // 6) deformable depthwise conv (vectorized 8 ch/thread)
  deform_kernel<<<2816, 256, 0, stream>>>(xffn, samp, cwT, conv_b, gridout);
  // 7) GEMM2 split-K x4: q2[z] = gridout @ wdbf^T (K=704 slices)
  gemm_nt<float><<<dim3(16, 8, 4), 256, 0, stream>>>(
      gridout, INTER, wdbf, INTER, q2, 2048, 1024, 704);
  // 8) out = sum of 4 partials
  reduce4<<<2048, 256, 0, stream>>>(q2, out);
}

// Round 6
// 211.174 us; speedup vs baseline: 1.8337x; 1.0466x over previous
//
#include <hip/hip_runtime.h>
#include <hip/hip_bf16.h>
#include <cstdint>
#include <cstddef>
#include <type_traits>

#define INTER 2816

typedef __bf16 bf16x8 __attribute__((ext_vector_type(8)));
typedef float f32x4 __attribute__((ext_vector_type(4)));
typedef unsigned short u16x8 __attribute__((ext_vector_type(8)));
using bf16 = __hip_bfloat16;
using u16 = unsigned short;

__device__ __forceinline__ u16 f2bu(float f) {
  bf16 h = __float2bfloat16(f);
  return *reinterpret_cast<u16*>(&h);
}
__device__ __forceinline__ float bu2f(u16 u) {
  bf16 h = *reinterpret_cast<bf16*>(&u);
  return __bfloat162float(h);
}

// Async global->LDS DMA, 16 B per lane. One call per thread = 1024 B per
// wave deposited at (wave-uniform LDS base) + lane*16 — LDS layout must be
// lane-order contiguous (it is: l == base + tid*8 u16).
__device__ __forceinline__ void async16(const u16* g, u16* l) {
  __builtin_amdgcn_global_load_lds(
      (const __attribute__((address_space(1))) unsigned int*)g,
      (__attribute__((address_space(3))) unsigned int*)l, 16, 0, 0);
}

// Stage 8 contiguous elements as bf16 (16B) — used by convert kernel.
__device__ __forceinline__ void stage8(u16* dst, const float* src) {
  const float4 a = *(const float4*)(src);
  const float4 b = *(const float4*)(src + 4);
  u16 tmp[8] = {f2bu(a.x), f2bu(a.y), f2bu(a.z), f2bu(a.w),
                f2bu(b.x), f2bu(b.y), f2bu(b.z), f2bu(b.w)};
  *(uint4*)dst = *(uint4*)tmp;
}

// ---------------------------------------------------------------------------
// One-shot f32 -> bf16 conversion of x, w_gate_up, w_down (8 elems/thread).
// ---------------------------------------------------------------------------
__global__ __launch_bounds__(256)
void convert_bf16(const float* __restrict__ x, const float* __restrict__ wgu,
                  const float* __restrict__ wd, u16* __restrict__ xbf,
                  u16* __restrict__ wgubf, u16* __restrict__ wdbf) {
  constexpr size_t S0 = (size_t)2048 * 1024;
  constexpr size_t S1 = (size_t)5632 * 1024;
  const size_t e0 = ((size_t)blockIdx.x * 256 + threadIdx.x) * 8;
  const float* src;
  u16* dst;
  size_t off;
  if (e0 < S0) {
    src = x; dst = xbf; off = e0;
  } else if (e0 < S0 + S1) {
    src = wgu; dst = wgubf; off = e0 - S0;
  } else {
    src = wd; dst = wdbf; off = e0 - S0 - S1;
  }
  stage8(dst + off, src + off);
}

// ---------------------------------------------------------------------------
// NT GEMM, 128x128 tile, 4 waves x (4x4) 16x16x32 mfma, BK=32, m97-style
// async global_load_lds staging (unpadded [128][32] LDS tiles).
// Split-K via grid.z: block z consumes cols [z*K, (z+1)*K), writes partial C
// at C + z*M*ldc.  M mult of 128, K mult of 32.
// ---------------------------------------------------------------------------
template <typename OT>
__global__ __launch_bounds__(256, 2)
void gemm_nt(const u16* __restrict__ A, int lda, const u16* __restrict__ Bt,
             int ldb, OT* __restrict__ C, int M, int ldc, int K) {
  __shared__ u16 As[128 * 32];
  __shared__ u16 Bs[128 * 32];
  const size_t koff = (size_t)blockIdx.z * K;
  A += koff;
  Bt += koff;
  C += (size_t)blockIdx.z * M * ldc;
  const int m0 = blockIdx.x * 128;
  const int n0 = blockIdx.y * 128;
  const int tid = threadIdx.x;
  const int lane = tid & 63;
  const int wv = tid >> 6;
  const int wm = wv & 1, wn = wv >> 1;
  const int lr = lane & 15;
  const int lq = lane >> 4;

  f32x4 acc[4][4];
#pragma unroll
  for (int i = 0; i < 4; ++i)
#pragma unroll
    for (int j = 0; j < 4; ++j) acc[i][j] = (f32x4){0.f, 0.f, 0.f, 0.f};

  // Staging map: op o covers rows [o*64, o*64+64); thread -> row o*64+tid/4,
  // col (tid%4)*8. LDS flat offset = o*2048 + tid*8 (lane-order contiguous).
  const int srow = tid >> 2;
  const int scol = (tid & 3) * 8;
  const u16* gA0 = A + (size_t)(m0 + srow) * lda + scol;
  const u16* gA1 = A + (size_t)(m0 + 64 + srow) * lda + scol;
  const u16* gB0 = Bt + (size_t)(n0 + srow) * ldb + scol;
  const u16* gB1 = Bt + (size_t)(n0 + 64 + srow) * ldb + scol;
  u16* lA0 = As + tid * 8;
  u16* lA1 = As + 2048 + tid * 8;
  u16* lB0 = Bs + tid * 8;
  u16* lB1 = Bs + 2048 + tid * 8;

  for (int kb = 0; kb < K; kb += 32) {
    async16(gA0 + kb, lA0);
    async16(gA1 + kb, lA1);
    async16(gB0 + kb, lB0);
    async16(gB1 + kb, lB1);
    __syncthreads();  // drains vmcnt before LDS reads
    bf16x8 af[4], bfr[4];
#pragma unroll
    for (int i = 0; i < 4; ++i)
      af[i] = *(const bf16x8*)(&As[(wm * 64 + i * 16 + lr) * 32 + lq * 8]);
#pragma unroll
    for (int j = 0; j < 4; ++j)
      bfr[j] = *(const bf16x8*)(&Bs[(wn * 64 + j * 16 + lr) * 32 + lq * 8]);
#pragma unroll
    for (int i = 0; i < 4; ++i)
#pragma unroll
      for (int j = 0; j < 4; ++j)
        acc[i][j] = __builtin_amdgcn_mfma_f32_16x16x32_bf16(af[i], bfr[j],
                                                            acc[i][j], 0, 0, 0);
    __syncthreads();
  }

#pragma unroll
  for (int i = 0; i < 4; ++i)
#pragma unroll
    for (int j = 0; j < 4; ++j) {
      const int col = n0 + wn * 64 + j * 16 + lr;
#pragma unroll
      for (int r = 0; r < 4; ++r) {
        const int row = m0 + wm * 64 + i * 16 + lq * 4 + r;
        const float v = acc[i][j][r];
        if constexpr (std::is_same_v<OT, float>) {
          C[(size_t)row * ldc + col] = v;
        } else {
          C[(size_t)row * ldc + col] = f2bu(v);
        }
      }
    }
}

// ---------------------------------------------------------------------------
// out[i] = sum of 4 split-K partials (f32), float4-vectorized.
// ---------------------------------------------------------------------------
__global__ void reduce4(const float* __restrict__ q2, float* __restrict__ out) {
  const size_t i = ((size_t)blockIdx.x * 256 + threadIdx.x) * 4;
  const size_t S = (size_t)2048 * 1024;
  float4 a = *(const float4*)(q2 + i);
  const float4 b = *(const float4*)(q2 + S + i);
  const float4 c = *(const float4*)(q2 + 2 * S + i);
  const float4 d = *(const float4*)(q2 + 3 * S + i);
  a.x += b.x + c.x + d.x;
  a.y += b.y + c.y + d.y;
  a.z += b.z + c.z + d.z;
  a.w += b.w + c.w + d.w;
  *(float4*)(out + i) = a;
}

// ---------------------------------------------------------------------------
// Fused gate/up GEMM + SiLU, 128x64 tile (64 gate + 64 up cols), async
// staging. Grid 16 x 44 = 704 blocks. 4 waves = 2(m) x 2(n).
// ---------------------------------------------------------------------------
__global__ __launch_bounds__(256, 2)
void gateup_gemm(const u16* __restrict__ x, const u16* __restrict__ wgu,
                 u16* __restrict__ xffn) {
  constexpr int K = 1024;
  __shared__ u16 As[128 * 32];
  __shared__ u16 Bgs[64 * 32];
  __shared__ u16 Bus[64 * 32];
  const int m0 = blockIdx.x * 128;
  const int n0 = blockIdx.y * 64;
  const int tid = threadIdx.x;
  const int lane = tid & 63;
  const int wv = tid >> 6;
  const int wm = wv & 1, wn = wv >> 1;
  const int lr = lane & 15;
  const int lq = lane >> 4;

  f32x4 accg[4][2], accu[4][2];
#pragma unroll
  for (int i = 0; i < 4; ++i)
#pragma unroll
    for (int j = 0; j < 2; ++j) {
      accg[i][j] = (f32x4){0.f, 0.f, 0.f, 0.f};
      accu[i][j] = (f32x4){0.f, 0.f, 0.f, 0.f};
    }

  const int srow = tid >> 2;
  const int scol = (tid & 3) * 8;
  const u16* gA0 = x + (size_t)(m0 + srow) * K + scol;
  const u16* gA1 = x + (size_t)(m0 + 64 + srow) * K + scol;
  const u16* gBg = wgu + (size_t)(n0 + srow) * K + scol;
  const u16* gBu = wgu + (size_t)(INTER + n0 + srow) * K + scol;
  u16* lA0 = As + tid * 8;
  u16* lA1 = As + 2048 + tid * 8;
  u16* lBg = Bgs + tid * 8;
  u16* lBu = Bus + tid * 8;

  for (int kb = 0; kb < K; kb += 32) {
    async16(gA0 + kb, lA0);
    async16(gA1 + kb, lA1);
    async16(gBg + kb, lBg);
    async16(gBu + kb, lBu);
    __syncthreads();
    bf16x8 af[4], bg[2], bu[2];
#pragma unroll
    for (int i = 0; i < 4; ++i)
      af[i] = *(const bf16x8*)(&As[(wm * 64 + i * 16 + lr) * 32 + lq * 8]);
#pragma unroll
    for (int j = 0; j < 2; ++j) {
      bg[j] = *(const bf16x8*)(&Bgs[(wn * 32 + j * 16 + lr) * 32 + lq * 8]);
      bu[j] = *(const bf16x8*)(&Bus[(wn * 32 + j * 16 + lr) * 32 + lq * 8]);
    }
#pragma unroll
    for (int i = 0; i < 4; ++i)
#pragma unroll
      for (int j = 0; j < 2; ++j) {
        accg[i][j] = __builtin_amdgcn_mfma_f32_16x16x32_bf16(af[i], bg[j],
                                                             accg[i][j], 0, 0, 0);
        accu[i][j] = __builtin_amdgcn_mfma_f32_16x16x32_bf16(af[i], bu[j],
                                                             accu[i][j], 0, 0, 0);
      }
    __syncthreads();
  }

#pragma unroll
  for (int i = 0; i < 4; ++i)
#pragma unroll
    for (int j = 0; j < 2; ++j) {
      const int col = n0 + wn * 32 + j * 16 + lr;
#pragma unroll
      for (int r = 0; r < 4; ++r) {
        const int row = m0 + wm * 64 + i * 16 + lq * 4 + r;
        const float g = accg[i][j][r];
        const float u = accu[i][j][r];
        const float s = g / (1.f + __expf(-g));
        xffn[(size_t)row * INTER + col] = f2bu(s * u);
      }
    }
}

// ---------------------------------------------------------------------------
// wm2[n, c] (128 x INTER bf16, zero-padded past 63): n = o*9+tap
// cwT[k, c] (9 x INTER, f32): conv_w[c, k] transposed
// ---------------------------------------------------------------------------
__global__ void prep_weights(const float* __restrict__ w_metric,
                             const float* __restrict__ conv_w,
                             u16* __restrict__ wm2, float* __restrict__ cwT) {
  const int c = blockIdx.x * 256 + threadIdx.x;
  const int y = blockIdx.y;
  if (y < 128) {
    float v = 0.f;
    if (y < 63) {
      const int o = y / 9, tap = y % 9;
      v = w_metric[((size_t)o * INTER + c) * 9 + tap];
    }
    wm2[(size_t)y * INTER + c] = f2bu(v);
  } else {
    const int k = y - 128;
    cwT[(size_t)k * INTER + c] = conv_w[(size_t)c * 9 + k];
  }
}

// ---------------------------------------------------------------------------
// Fused: sum 8 split-K partials of q + 9-tap shifted sum + offsets + sample
// records. One block (1 wave) per 64 pixels; cooperative coalesced LDS load
// of the 130-pixel neighbor window (64 cols), then per-lane tap-sum from LDS
// (row stride 65 words -> conflict-free).
// ---------------------------------------------------------------------------
__global__ __launch_bounds__(64)
void offsets_fused(const float* __restrict__ q,   // [8][2048][128]
                   const float* __restrict__ b_metric,
                   int4* __restrict__ samp) {
  __shared__ float lds[130 * 65];
  const int chunk = blockIdx.x;      // 0..31
  const int b = chunk >> 4;
  const int c0 = (chunk & 15) * 64;  // batch-local first pixel of this block
  const int t = threadIdx.x;         // 0..63

  for (int v = t; v < 130 * 16; v += 64) {
    const int row = v >> 4;
    const int c4 = (v & 15) * 4;
    int pg = c0 - 33 + row;
    pg = min(max(pg, 0), 1023);
    const float* src = q + ((size_t)b * 1024 + pg) * 128 + c4;
    float4 s = *(const float4*)(src);
#pragma unroll
    for (int ks = 1; ks < 8; ++ks) {
      const float4 vv = *(const float4*)(src + (size_t)ks * 2048 * 128);
      s.x += vv.x; s.y += vv.y; s.z += vv.z; s.w += vv.w;
    }
    float* d = &lds[row * 65 + c4];
    d[0] = s.x; d[1] = s.y; d[2] = s.z; d[3] = s.w;
  }
  __syncthreads();

  const int pix = c0 + t;
  const int i = pix >> 5, j = pix & 31;
  float p[7];
#pragma unroll
  for (int o = 0; o < 7; ++o) p[o] = b_metric[o];
#pragma unroll
  for (int tap = 0; tap < 9; ++tap) {
    const int dy = tap / 3 - 1, dx = tap % 3 - 1;
    const int ii = i + dy, jj = j + dx;
    if ((unsigned)ii < 32u && (unsigned)jj < 32u) {
      const float* r = &lds[(t + 33 + dy * 32 + dx) * 65 + tap];
#pragma unroll
      for (int o = 0; o < 7; ++o) p[o] += r[o * 9];
    }
  }
  const float m00 = p[0], m01 = p[1], m10 = p[2], m11 = p[3];
  const float dry = p[4], drx = p[5];
  const float sc = tanhf(p[6]);
#pragma unroll
  for (int k = 0; k < 9; ++k) {
    const float pyk = (float)(k / 3 - 1), pxk = (float)(k % 3 - 1);
    const float offy = sc * (m00 * pyk + m01 * pxk) + dry;
    const float offx = sc * (m10 * pyk + m11 * pxk) + drx;
    const float posy = (float)i + pyk + offy;
    const float posx = (float)j + pxk + offx;
    const float y0f = floorf(posy), x0f = floorf(posx);
    int4 s;
    s.x = (int)y0f;
    s.y = (int)x0f;
    s.z = __float_as_int(posy - y0f);
    s.w = __float_as_int(posx - x0f);
    samp[((size_t)b * 9 + k) * 1024 + pix] = s;
  }
}

// ---------------------------------------------------------------------------
// Deformable depthwise conv, 8 channels/thread with 16B gathers.
// ---------------------------------------------------------------------------
__global__ __launch_bounds__(256)
void deform_kernel(const u16* __restrict__ xffn,
                   const int4* __restrict__ samp,
                   const float* __restrict__ cwT,
                   const float* __restrict__ conv_b,
                   u16* __restrict__ gridout) {
  const unsigned t = blockIdx.x * 256 + threadIdx.x;
  const unsigned pix = t / 352u;
  const unsigned cv = t - pix * 352u;
  const int c0 = cv * 8;
  const int b = pix >> 10, l = pix & 1023;

  float acc[8];
  {
    const float4 b0 = *(const float4*)(&conv_b[c0]);
    const float4 b1 = *(const float4*)(&conv_b[c0 + 4]);
    acc[0] = b0.x; acc[1] = b0.y; acc[2] = b0.z; acc[3] = b0.w;
    acc[4] = b1.x; acc[5] = b1.y; acc[6] = b1.z; acc[7] = b1.w;
  }
  const size_t pixbase = (size_t)b * 1024;
#pragma unroll
  for (int k = 0; k < 9; ++k) {
    const int4 s = samp[((size_t)b * 9 + k) * 1024 + l];
    const int y0 = s.x, x0 = s.y;
    const float ty = __int_as_float(s.z), tx = __int_as_float(s.w);
    const int y1 = y0 + 1, x1 = x0 + 1;
    const float vy0 = ((unsigned)y0 < 32u) ? 1.f : 0.f;
    const float vy1 = ((unsigned)y1 < 32u) ? 1.f : 0.f;
    const float vx0 = ((unsigned)x0 < 32u) ? 1.f : 0.f;
    const float vx1 = ((unsigned)x1 < 32u) ? 1.f : 0.f;
    const float w00 = (1.f - ty) * (1.f - tx) * vy0 * vx0;
    const float w01 = (1.f - ty) * tx * vy0 * vx1;
    const float w10 = ty * (1.f - tx) * vy1 * vx0;
    const float w11 = ty * tx * vy1 * vx1;
    const int cy0 = min(max(y0, 0), 31), cy1 = min(max(y1, 0), 31);
    const int cx0 = min(max(x0, 0), 31), cx1 = min(max(x1, 0), 31);
    const u16x8 v00 = *(const u16x8*)(&xffn[(pixbase + cy0 * 32 + cx0) * INTER + c0]);
    const u16x8 v01 = *(const u16x8*)(&xffn[(pixbase + cy0 * 32 + cx1) * INTER + c0]);
    const u16x8 v10 = *(const u16x8*)(&xffn[(pixbase + cy1 * 32 + cx0) * INTER + c0]);
    const u16x8 v11 = *(const u16x8*)(&xffn[(pixbase + cy1 * 32 + cx1) * INTER + c0]);
    const float4 cwa = *(const float4*)(&cwT[(size_t)k * INTER + c0]);
    const float4 cwb = *(const float4*)(&cwT[(size_t)k * INTER + c0 + 4]);
    const float cw[8] = {cwa.x, cwa.y, cwa.z, cwa.w, cwb.x, cwb.y, cwb.z, cwb.w};
#pragma unroll
    for (int e = 0; e < 8; ++e) {
      const float bl = w00 * bu2f(v00[e]) + w01 * bu2f(v01[e]) +
                       w10 * bu2f(v10[e]) + w11 * bu2f(v11[e]);
      acc[e] += bl * cw[e];
    }
  }
  u16 outv[8];
#pragma unroll
  for (int e = 0; e < 8; ++e) outv[e] = f2bu(acc[e]);
  *(uint4*)(&gridout[(pixbase + l) * INTER + c0]) = *(uint4*)outv;
}

// ---------------------------------------------------------------------------
extern "C" void kernel_launch(void* const* d_in, const int* in_sizes, int n_in,
                              void* d_out, int out_size, void* d_ws,
                              size_t ws_size, hipStream_t stream) {
  const float* x         = (const float*)d_in[0];
  const float* w_gate_up = (const float*)d_in[1];
  const float* w_metric  = (const float*)d_in[2];
  const float* b_metric  = (const float*)d_in[3];
  const float* conv_w    = (const float*)d_in[4];
  const float* conv_b    = (const float*)d_in[5];
  const float* w_down    = (const float*)d_in[6];
  float* out = (float*)d_out;

  // Workspace (~50 MB peak). Lifetimes:
  //   gridout [0, 11.53)  bf16   step 6 -> 7
  //   q2      [12, 44)    f32    step 7 -> 8; region shared (earlier steps):
  //     xffn   [12, 23.6)  bf16  step 2 -> 6
  //     xbf    [24, 28.2)  bf16  step 1 -> 2
  //     wgubf  [28.25, 39.8) bf16 step 1 -> 2
  //     q_conv [28.25, 36.25) f32 step 4 -> 5 (overlays dead wgubf)
  //     wm2    [40, 40.72) bf16  step 3 -> 4
  //     cwT    [41, 41.11) f32   step 3 -> 6
  //     samp   [42, 42.3)  int4  step 5 -> 6
  //   wdbf    [44, 49.8)  bf16   step 1 -> 7
  char* w = (char*)d_ws;
  u16* gridout  = (u16*)(w);
  float* q2     = (float*)(w + (12u << 20));
  u16* xffn     = (u16*)(w + (12u << 20));
  u16* xbf      = (u16*)(w + (24u << 20));
  u16* wgubf    = (u16*)(w + (28u << 20) + (256u << 10));
  float* q_conv = (float*)(w + (28u << 20) + (256u << 10));
  u16* wm2      = (u16*)(w + (40u << 20));
  float* cwT    = (float*)(w + (41u << 20));
  int4* samp    = (int4*)(w + (42u << 20));
  u16* wdbf     = (u16*)(w + (44u << 20));

  // 1) one-shot bf16 conversion of x, w_gate_up, w_down
  convert_bf16<<<5248, 256, 0, stream>>>(x, w_gate_up, w_down,
                                         xbf, wgubf, wdbf);
  // 2) x_ffn = silu(x@Wg^T) * (x@Wu^T)   (128x64 tiles, 704 blocks)
  gateup_gemm<<<dim3(16, 44), 256, 0, stream>>>(xbf, wgubf, xffn);
  // 3) weight repacks
  prep_weights<<<dim3(11, 137), 256, 0, stream>>>(w_metric, conv_w, wm2, cwT);
  // 4) metric conv as GEMM, split-K x8 partials (2048 x 128 x 352 each)
  gemm_nt<float><<<dim3(16, 1, 8), 256, 0, stream>>>(
      xffn, INTER, wm2, INTER, q_conv, 2048, 128, 352);
  // 5) fused partial-sum + tap-sum + offsets -> sample records
  offsets_fused<<<32, 64, 0, stream>>>(q_conv, b_metric, samp);
  // 6) deformable depthwise conv (vectorized 8 ch/thread)
  deform_kernel<<<2816, 256, 0, stream>>>(xffn, samp, cwT, conv_b, gridout);
  // 7) GEMM2 split-K x4: q2[z] = gridout @ wdbf^T (K=704 slices)
  gemm_nt<float><<<dim3(16, 8, 4), 256, 0, stream>>>(
      gridout, INTER, wdbf, INTER, q2, 2048, 1024, 704);
  // 8) out = sum of 4 partials
  reduce4<<<2048, 256, 0, stream>>>(q2, out);
}

// Round 7
// 211.118 us; speedup vs baseline: 1.8341x; 1.0003x over previous
//
#include <hip/hip_runtime.h>
#include <hip/hip_bf16.h>
#include <cstdint>
#include <cstddef>
#include <type_traits>

#define INTER 2816

typedef __bf16 bf16x8 __attribute__((ext_vector_type(8)));
typedef float f32x4 __attribute__((ext_vector_type(4)));
typedef unsigned short u16x8 __attribute__((ext_vector_type(8)));
using bf16 = __hip_bfloat16;
using u16 = unsigned short;

__device__ __forceinline__ u16 f2bu(float f) {
  bf16 h = __float2bfloat16(f);
  return *reinterpret_cast<u16*>(&h);
}
__device__ __forceinline__ float bu2f(u16 u) {
  bf16 h = *reinterpret_cast<bf16*>(&u);
  return __bfloat162float(h);
}

// Async global->LDS DMA, 16 B per lane (wave-uniform base + lane*16).
__device__ __forceinline__ void async16(const u16* g, u16* l) {
  __builtin_amdgcn_global_load_lds(
      (const __attribute__((address_space(1))) unsigned int*)g,
      (__attribute__((address_space(3))) unsigned int*)l, 16, 0, 0);
}

// Stage 8 contiguous f32 as bf16 (16B out).
__device__ __forceinline__ void stage8(u16* dst, const float* src) {
  const float4 a = *(const float4*)(src);
  const float4 b = *(const float4*)(src + 4);
  u16 tmp[8] = {f2bu(a.x), f2bu(a.y), f2bu(a.z), f2bu(a.w),
                f2bu(b.x), f2bu(b.y), f2bu(b.z), f2bu(b.w)};
  *(uint4*)dst = *(uint4*)tmp;
}

// ---------------------------------------------------------------------------
// Fused one-shot prep: f32->bf16 conversion of x/wgu/wd (8 elem/thread,
// blocks 0..5247) + metric/conv weight repack (blocks 5248..6754).
// ---------------------------------------------------------------------------
__global__ __launch_bounds__(256)
void prep_all(const float* __restrict__ x, const float* __restrict__ wgu,
              const float* __restrict__ wd, const float* __restrict__ w_metric,
              const float* __restrict__ conv_w, u16* __restrict__ xbf,
              u16* __restrict__ wgubf, u16* __restrict__ wdbf,
              u16* __restrict__ wm2, float* __restrict__ cwT) {
  constexpr size_t S0 = (size_t)2048 * 1024;
  constexpr size_t S1 = (size_t)5632 * 1024;
  constexpr size_t S2 = (size_t)1024 * 2816;
  constexpr size_t NCONV_THREADS = (S0 + S1 + S2) / 8;  // 1343488 = 5248 blks
  const size_t t = (size_t)blockIdx.x * 256 + threadIdx.x;
  if (t < NCONV_THREADS) {
    const size_t e0 = t * 8;
    const float* src;
    u16* dst;
    size_t off;
    if (e0 < S0) {
      src = x; dst = xbf; off = e0;
    } else if (e0 < S0 + S1) {
      src = wgu; dst = wgubf; off = e0 - S0;
    } else {
      src = wd; dst = wdbf; off = e0 - S0 - S1;
    }
    stage8(dst + off, src + off);
  } else {
    const unsigned p = (unsigned)(t - NCONV_THREADS);  // 0..385791
    const unsigned y = p / 2816u;                      // 0..136
    const unsigned c = p - y * 2816u;
    if (y < 128) {
      float v = 0.f;
      if (y < 63) {
        const unsigned o = y / 9, tap = y - o * 9;
        v = w_metric[((size_t)o * INTER + c) * 9 + tap];
      }
      wm2[(size_t)y * INTER + c] = f2bu(v);
    } else {
      const unsigned k = y - 128;
      cwT[(size_t)k * INTER + c] = conv_w[(size_t)c * 9 + k];
    }
  }
}

// ---------------------------------------------------------------------------
// NT GEMM, 128x128 tile, 4 waves x (4x4) 16x16x32 mfma, BK=32, async
// global_load_lds staging. Split-K via grid.z (partial C at z*M*ldc).
// 3 blocks/CU: ~120 regs/thread fits the 3-wave/EU budget.
// ---------------------------------------------------------------------------
template <typename OT>
__global__ __launch_bounds__(256, 3)
void gemm_nt(const u16* __restrict__ A, int lda, const u16* __restrict__ Bt,
             int ldb, OT* __restrict__ C, int M, int ldc, int K) {
  __shared__ u16 As[128 * 32];
  __shared__ u16 Bs[128 * 32];
  const size_t koff = (size_t)blockIdx.z * K;
  A += koff;
  Bt += koff;
  C += (size_t)blockIdx.z * M * ldc;
  const int m0 = blockIdx.x * 128;
  const int n0 = blockIdx.y * 128;
  const int tid = threadIdx.x;
  const int lane = tid & 63;
  const int wv = tid >> 6;
  const int wm = wv & 1, wn = wv >> 1;
  const int lr = lane & 15;
  const int lq = lane >> 4;

  f32x4 acc[4][4];
#pragma unroll
  for (int i = 0; i < 4; ++i)
#pragma unroll
    for (int j = 0; j < 4; ++j) acc[i][j] = (f32x4){0.f, 0.f, 0.f, 0.f};

  const int srow = tid >> 2;
  const int scol = (tid & 3) * 8;
  const u16* gA0 = A + (size_t)(m0 + srow) * lda + scol;
  const u16* gA1 = A + (size_t)(m0 + 64 + srow) * lda + scol;
  const u16* gB0 = Bt + (size_t)(n0 + srow) * ldb + scol;
  const u16* gB1 = Bt + (size_t)(n0 + 64 + srow) * ldb + scol;
  u16* lA0 = As + tid * 8;
  u16* lA1 = As + 2048 + tid * 8;
  u16* lB0 = Bs + tid * 8;
  u16* lB1 = Bs + 2048 + tid * 8;

  for (int kb = 0; kb < K; kb += 32) {
    async16(gA0 + kb, lA0);
    async16(gA1 + kb, lA1);
    async16(gB0 + kb, lB0);
    async16(gB1 + kb, lB1);
    __syncthreads();
    bf16x8 af[4], bfr[4];
#pragma unroll
    for (int i = 0; i < 4; ++i)
      af[i] = *(const bf16x8*)(&As[(wm * 64 + i * 16 + lr) * 32 + lq * 8]);
#pragma unroll
    for (int j = 0; j < 4; ++j)
      bfr[j] = *(const bf16x8*)(&Bs[(wn * 64 + j * 16 + lr) * 32 + lq * 8]);
#pragma unroll
    for (int i = 0; i < 4; ++i)
#pragma unroll
      for (int j = 0; j < 4; ++j)
        acc[i][j] = __builtin_amdgcn_mfma_f32_16x16x32_bf16(af[i], bfr[j],
                                                            acc[i][j], 0, 0, 0);
    __syncthreads();
  }

#pragma unroll
  for (int i = 0; i < 4; ++i)
#pragma unroll
    for (int j = 0; j < 4; ++j) {
      const int col = n0 + wn * 64 + j * 16 + lr;
#pragma unroll
      for (int r = 0; r < 4; ++r) {
        const int row = m0 + wm * 64 + i * 16 + lq * 4 + r;
        const float v = acc[i][j][r];
        if constexpr (std::is_same_v<OT, float>) {
          C[(size_t)row * ldc + col] = v;
        } else {
          C[(size_t)row * ldc + col] = f2bu(v);
        }
      }
    }
}

// ---------------------------------------------------------------------------
// out[i] = sum of 4 split-K partials (f32), float4-vectorized.
// ---------------------------------------------------------------------------
__global__ void reduce4(const float* __restrict__ q2, float* __restrict__ out) {
  const size_t i = ((size_t)blockIdx.x * 256 + threadIdx.x) * 4;
  const size_t S = (size_t)2048 * 1024;
  float4 a = *(const float4*)(q2 + i);
  const float4 b = *(const float4*)(q2 + S + i);
  const float4 c = *(const float4*)(q2 + 2 * S + i);
  const float4 d = *(const float4*)(q2 + 3 * S + i);
  a.x += b.x + c.x + d.x;
  a.y += b.y + c.y + d.y;
  a.z += b.z + c.z + d.z;
  a.w += b.w + c.w + d.w;
  *(float4*)(out + i) = a;
}

// ---------------------------------------------------------------------------
// Fused gate/up GEMM + SiLU, 128x64 tile (64 gate + 64 up cols), async
// staging. Grid 16 x 44 = 704 blocks at 3 blocks/CU.
// ---------------------------------------------------------------------------
__global__ __launch_bounds__(256, 3)
void gateup_gemm(const u16* __restrict__ x, const u16* __restrict__ wgu,
                 u16* __restrict__ xffn) {
  constexpr int K = 1024;
  __shared__ u16 As[128 * 32];
  __shared__ u16 Bgs[64 * 32];
  __shared__ u16 Bus[64 * 32];
  const int m0 = blockIdx.x * 128;
  const int n0 = blockIdx.y * 64;
  const int tid = threadIdx.x;
  const int lane = tid & 63;
  const int wv = tid >> 6;
  const int wm = wv & 1, wn = wv >> 1;
  const int lr = lane & 15;
  const int lq = lane >> 4;

  f32x4 accg[4][2], accu[4][2];
#pragma unroll
  for (int i = 0; i < 4; ++i)
#pragma unroll
    for (int j = 0; j < 2; ++j) {
      accg[i][j] = (f32x4){0.f, 0.f, 0.f, 0.f};
      accu[i][j] = (f32x4){0.f, 0.f, 0.f, 0.f};
    }

  const int srow = tid >> 2;
  const int scol = (tid & 3) * 8;
  const u16* gA0 = x + (size_t)(m0 + srow) * K + scol;
  const u16* gA1 = x + (size_t)(m0 + 64 + srow) * K + scol;
  const u16* gBg = wgu + (size_t)(n0 + srow) * K + scol;
  const u16* gBu = wgu + (size_t)(INTER + n0 + srow) * K + scol;
  u16* lA0 = As + tid * 8;
  u16* lA1 = As + 2048 + tid * 8;
  u16* lBg = Bgs + tid * 8;
  u16* lBu = Bus + tid * 8;

  for (int kb = 0; kb < K; kb += 32) {
    async16(gA0 + kb, lA0);
    async16(gA1 + kb, lA1);
    async16(gBg + kb, lBg);
    async16(gBu + kb, lBu);
    __syncthreads();
    bf16x8 af[4], bg[2], bu[2];
#pragma unroll
    for (int i = 0; i < 4; ++i)
      af[i] = *(const bf16x8*)(&As[(wm * 64 + i * 16 + lr) * 32 + lq * 8]);
#pragma unroll
    for (int j = 0; j < 2; ++j) {
      bg[j] = *(const bf16x8*)(&Bgs[(wn * 32 + j * 16 + lr) * 32 + lq * 8]);
      bu[j] = *(const bf16x8*)(&Bus[(wn * 32 + j * 16 + lr) * 32 + lq * 8]);
    }
#pragma unroll
    for (int i = 0; i < 4; ++i)
#pragma unroll
      for (int j = 0; j < 2; ++j) {
        accg[i][j] = __builtin_amdgcn_mfma_f32_16x16x32_bf16(af[i], bg[j],
                                                             accg[i][j], 0, 0, 0);
        accu[i][j] = __builtin_amdgcn_mfma_f32_16x16x32_bf16(af[i], bu[j],
                                                             accu[i][j], 0, 0, 0);
      }
    __syncthreads();
  }

#pragma unroll
  for (int i = 0; i < 4; ++i)
#pragma unroll
    for (int j = 0; j < 2; ++j) {
      const int col = n0 + wn * 32 + j * 16 + lr;
#pragma unroll
      for (int r = 0; r < 4; ++r) {
        const int row = m0 + wm * 64 + i * 16 + lq * 4 + r;
        const float g = accg[i][j][r];
        const float u = accu[i][j][r];
        const float s = g / (1.f + __expf(-g));
        xffn[(size_t)row * INTER + col] = f2bu(s * u);
      }
    }
}

// ---------------------------------------------------------------------------
// Fused: sum 8 split-K partials of q + 9-tap shifted sum + offsets + sample
// records. One wave per 64 pixels; coalesced LDS window load.
// ---------------------------------------------------------------------------
__global__ __launch_bounds__(64)
void offsets_fused(const float* __restrict__ q,   // [8][2048][128]
                   const float* __restrict__ b_metric,
                   int4* __restrict__ samp) {
  __shared__ float lds[130 * 65];
  const int chunk = blockIdx.x;      // 0..31
  const int b = chunk >> 4;
  const int c0 = (chunk & 15) * 64;
  const int t = threadIdx.x;

  for (int v = t; v < 130 * 16; v += 64) {
    const int row = v >> 4;
    const int c4 = (v & 15) * 4;
    int pg = c0 - 33 + row;
    pg = min(max(pg, 0), 1023);
    const float* src = q + ((size_t)b * 1024 + pg) * 128 + c4;
    float4 s = *(const float4*)(src);
#pragma unroll
    for (int ks = 1; ks < 8; ++ks) {
      const float4 vv = *(const float4*)(src + (size_t)ks * 2048 * 128);
      s.x += vv.x; s.y += vv.y; s.z += vv.z; s.w += vv.w;
    }
    float* d = &lds[row * 65 + c4];
    d[0] = s.x; d[1] = s.y; d[2] = s.z; d[3] = s.w;
  }
  __syncthreads();

  const int pix = c0 + t;
  const int i = pix >> 5, j = pix & 31;
  float p[7];
#pragma unroll
  for (int o = 0; o < 7; ++o) p[o] = b_metric[o];
#pragma unroll
  for (int tap = 0; tap < 9; ++tap) {
    const int dy = tap / 3 - 1, dx = tap % 3 - 1;
    const int ii = i + dy, jj = j + dx;
    if ((unsigned)ii < 32u && (unsigned)jj < 32u) {
      const float* r = &lds[(t + 33 + dy * 32 + dx) * 65 + tap];
#pragma unroll
      for (int o = 0; o < 7; ++o) p[o] += r[o * 9];
    }
  }
  const float m00 = p[0], m01 = p[1], m10 = p[2], m11 = p[3];
  const float dry = p[4], drx = p[5];
  const float sc = tanhf(p[6]);
#pragma unroll
  for (int k = 0; k < 9; ++k) {
    const float pyk = (float)(k / 3 - 1), pxk = (float)(k % 3 - 1);
    const float offy = sc * (m00 * pyk + m01 * pxk) + dry;
    const float offx = sc * (m10 * pyk + m11 * pxk) + drx;
    const float posy = (float)i + pyk + offy;
    const float posx = (float)j + pxk + offx;
    const float y0f = floorf(posy), x0f = floorf(posx);
    int4 s;
    s.x = (int)y0f;
    s.y = (int)x0f;
    s.z = __float_as_int(posy - y0f);
    s.w = __float_as_int(posx - x0f);
    samp[((size_t)b * 9 + k) * 1024 + pix] = s;
  }
}

// ---------------------------------------------------------------------------
// Deformable depthwise conv, 8 channels/thread with 16B gathers.
// ---------------------------------------------------------------------------
__global__ __launch_bounds__(256)
void deform_kernel(const u16* __restrict__ xffn,
                   const int4* __restrict__ samp,
                   const float* __restrict__ cwT,
                   const float* __restrict__ conv_b,
                   u16* __restrict__ gridout) {
  const unsigned t = blockIdx.x * 256 + threadIdx.x;
  const unsigned pix = t / 352u;
  const unsigned cv = t - pix * 352u;
  const int c0 = cv * 8;
  const int b = pix >> 10, l = pix & 1023;

  float acc[8];
  {
    const float4 b0 = *(const float4*)(&conv_b[c0]);
    const float4 b1 = *(const float4*)(&conv_b[c0 + 4]);
    acc[0] = b0.x; acc[1] = b0.y; acc[2] = b0.z; acc[3] = b0.w;
    acc[4] = b1.x; acc[5] = b1.y; acc[6] = b1.z; acc[7] = b1.w;
  }
  const size_t pixbase = (size_t)b * 1024;
#pragma unroll
  for (int k = 0; k < 9; ++k) {
    const int4 s = samp[((size_t)b * 9 + k) * 1024 + l];
    const int y0 = s.x, x0 = s.y;
    const float ty = __int_as_float(s.z), tx = __int_as_float(s.w);
    const int y1 = y0 + 1, x1 = x0 + 1;
    const float vy0 = ((unsigned)y0 < 32u) ? 1.f : 0.f;
    const float vy1 = ((unsigned)y1 < 32u) ? 1.f : 0.f;
    const float vx0 = ((unsigned)x0 < 32u) ? 1.f : 0.f;
    const float vx1 = ((unsigned)x1 < 32u) ? 1.f : 0.f;
    const float w00 = (1.f - ty) * (1.f - tx) * vy0 * vx0;
    const float w01 = (1.f - ty) * tx * vy0 * vx1;
    const float w10 = ty * (1.f - tx) * vy1 * vx0;
    const float w11 = ty * tx * vy1 * vx1;
    const int cy0 = min(max(y0, 0), 31), cy1 = min(max(y1, 0), 31);
    const int cx0 = min(max(x0, 0), 31), cx1 = min(max(x1, 0), 31);
    const u16x8 v00 = *(const u16x8*)(&xffn[(pixbase + cy0 * 32 + cx0) * INTER + c0]);
    const u16x8 v01 = *(const u16x8*)(&xffn[(pixbase + cy0 * 32 + cx1) * INTER + c0]);
    const u16x8 v10 = *(const u16x8*)(&xffn[(pixbase + cy1 * 32 + cx0) * INTER + c0]);
    const u16x8 v11 = *(const u16x8*)(&xffn[(pixbase + cy1 * 32 + cx1) * INTER + c0]);
    const float4 cwa = *(const float4*)(&cwT[(size_t)k * INTER + c0]);
    const float4 cwb = *(const float4*)(&cwT[(size_t)k * INTER + c0 + 4]);
    const float cw[8] = {cwa.x, cwa.y, cwa.z, cwa.w, cwb.x, cwb.y, cwb.z, cwb.w};
#pragma unroll
    for (int e = 0; e < 8; ++e) {
      const float bl = w00 * bu2f(v00[e]) + w01 * bu2f(v01[e]) +
                       w10 * bu2f(v10[e]) + w11 * bu2f(v11[e]);
      acc[e] += bl * cw[e];
    }
  }
  u16 outv[8];
#pragma unroll
  for (int e = 0; e < 8; ++e) outv[e] = f2bu(acc[e]);
  *(uint4*)(&gridout[(pixbase + l) * INTER + c0]) = *(uint4*)outv;
}

// ---------------------------------------------------------------------------
extern "C" void kernel_launch(void* const* d_in, const int* in_sizes, int n_in,
                              void* d_out, int out_size, void* d_ws,
                              size_t ws_size, hipStream_t stream) {
  const float* x         = (const float*)d_in[0];
  const float* w_gate_up = (const float*)d_in[1];
  const float* w_metric  = (const float*)d_in[2];
  const float* b_metric  = (const float*)d_in[3];
  const float* conv_w    = (const float*)d_in[4];
  const float* conv_b    = (const float*)d_in[5];
  const float* w_down    = (const float*)d_in[6];
  float* out = (float*)d_out;

  // Workspace (~50 MB peak). Lifetimes:
  //   gridout [0, 11.53)  bf16   step 5 -> 6
  //   q2      [12, 44)    f32    step 6 -> 7; region shared (earlier steps):
  //     xffn   [12, 23.6)  bf16  step 2 -> 5
  //     xbf    [24, 28.2)  bf16  step 1 -> 2
  //     wgubf  [28.25, 39.8) bf16 step 1 -> 2
  //     q_conv [28.25, 36.25) f32 step 3 -> 4 (overlays dead wgubf)
  //     wm2    [40, 40.72) bf16  step 1 -> 3
  //     cwT    [41, 41.11) f32   step 1 -> 5
  //     samp   [42, 42.3)  int4  step 4 -> 5
  //   wdbf    [44, 49.8)  bf16   step 1 -> 6
  char* w = (char*)d_ws;
  u16* gridout  = (u16*)(w);
  float* q2     = (float*)(w + (12u << 20));
  u16* xffn     = (u16*)(w + (12u << 20));
  u16* xbf      = (u16*)(w + (24u << 20));
  u16* wgubf    = (u16*)(w + (28u << 20) + (256u << 10));
  float* q_conv = (float*)(w + (28u << 20) + (256u << 10));
  u16* wm2      = (u16*)(w + (40u << 20));
  float* cwT    = (float*)(w + (41u << 20));
  int4* samp    = (int4*)(w + (42u << 20));
  u16* wdbf     = (u16*)(w + (44u << 20));

  // 1) fused bf16 conversions + weight repacks (5248 conv blocks + 1507 prep)
  prep_all<<<6755, 256, 0, stream>>>(x, w_gate_up, w_down, w_metric, conv_w,
                                     xbf, wgubf, wdbf, wm2, cwT);
  // 2) x_ffn = silu(x@Wg^T) * (x@Wu^T)   (128x64 tiles, 704 blocks, 3/CU)
  gateup_gemm<<<dim3(16, 44), 256, 0, stream>>>(xbf, wgubf, xffn);
  // 3) metric conv as GEMM, split-K x8 partials (2048 x 128 x 352 each)
  gemm_nt<float><<<dim3(16, 1, 8), 256, 0, stream>>>(
      xffn, INTER, wm2, INTER, q_conv, 2048, 128, 352);
  // 4) fused partial-sum + tap-sum + offsets -> sample records
  offsets_fused<<<32, 64, 0, stream>>>(q_conv, b_metric, samp);
  // 5) deformable depthwise conv (vectorized 8 ch/thread)
  deform_kernel<<<2816, 256, 0, stream>>>(xffn, samp, cwT, conv_b, gridout);
  // 6) GEMM2 split-K x4: q2[z] = gridout @ wdbf^T (K=704 slices, 512 blocks)
  gemm_nt<float><<<dim3(16, 8, 4), 256, 0, stream>>>(
      gridout, INTER, wdbf, INTER, q2, 2048, 1024, 704);
  // 7) out = sum of 4 partials
  reduce4<<<2048, 256, 0, stream>>>(q2, out);
}